// Round 9
// baseline (387.619 us; speedup 1.0000x reference)
//
#include <hip/hip_runtime.h>
#include <hip/hip_bf16.h>

#define BATCH   8
#define C_DIM   512
#define HWD     56
#define NPIX    3136   // 56*56
#define PW      14
#define PP      196    // 14*14
#define M_TOT   588    // 3*196
#define BM_ROWS 4704   // 8*588
#define BM_PAD  4736   // padded to 37*128
#define HEADS   8
#define HD      64
#define N_SEQ   3136
#define SM_SCALE 0.125f
// SM_SCALE * log2(e): folded into Q at the q-GEMM epilogue, so the attention
// inner loop computes p = exp2(s) with NO multiply at all.
#define SM_SCALE_LOG2E 0.1803368801111204f

// attention LDS geometry: K ONLY (V is read from global/L2 — dropping Vs
// halves LDS to 80.5 KB -> 2 blocks/CU -> 32 waves/CU, the TLP that hides
// the per-step latency chain the compiler refuses to pipeline in-register).
#define KS_STRIDE 68            // shorts per K row (34 words: frag reads <=2-way)
#define KS_ROWS   592           // 588 + 4 zero pad rows
#define ATTN_LDS_SHORTS (KS_ROWS * KS_STRIDE)    // 40256
#define ATTN_LDS_BYTES  (ATTN_LDS_SHORTS * 2)    // 80512  (2x80512 <= 160KB)
#define QROWS_PER_BLK 392       // 3136 / 8 n-splits

typedef __attribute__((ext_vector_type(8))) short bf16x8;
typedef __attribute__((ext_vector_type(4))) short bf16x4;
typedef __attribute__((ext_vector_type(4))) float f32x4;

__device__ __forceinline__ short f2bs(float f) {
    __hip_bfloat16 h = __float2bfloat16(f);
    return *reinterpret_cast<short*>(&h);
}
__device__ __forceinline__ unsigned pkbf(float lo, float hi) {
    __hip_bfloat162 t = __float22bfloat162_rn(make_float2(lo, hi));
    return *reinterpret_cast<unsigned*>(&t);
}
__device__ __forceinline__ float fexp2(float x) {
#if __has_builtin(__builtin_amdgcn_exp2f)
    return __builtin_amdgcn_exp2f(x);
#else
    return exp2f(x);
#endif
}

// 16x16x16 bf16 MFMA (K=16): B-operand layout k=quad*4+jj, n=l15 — matches
// the C/D layout of our S^T tiles directly (no transpose needed for PV).
__device__ __forceinline__ f32x4 mfma16(bf16x4 a, bf16x4 b, f32x4 c) {
#if __has_builtin(__builtin_amdgcn_mfma_f32_16x16x16bf16_1k)
    return __builtin_amdgcn_mfma_f32_16x16x16bf16_1k(a, b, c, 0, 0, 0);
#elif __has_builtin(__builtin_amdgcn_mfma_f32_16x16x16_bf16)
    return __builtin_amdgcn_mfma_f32_16x16x16_bf16(a, b, c, 0, 0, 0);
#else
    asm volatile("v_mfma_f32_16x16x16_bf16 %0, %1, %2, %0\n\ts_nop 7\n\ts_nop 1"
                 : "+v"(c) : "v"(a), "v"(b));
    return c;
#endif
}

// async 16B global->LDS copy (m97 pattern, wave-uniform LDS base).
__device__ __forceinline__ void gl_lds16(const void* g, void* l) {
    __builtin_amdgcn_global_load_lds(
        (const __attribute__((address_space(1))) void*)g,
        (__attribute__((address_space(3))) void*)l, 16, 0, 0);
}

// ===========================================================================
// K1: fused front-end — branches (4096) ∪ xpose (3136) ∪ wconv (768).
// ===========================================================================

__device__ __forceinline__ void branches_body(
    int c, int b, int tid, float* sbuf,
    const float* __restrict__ x,
    const float* __restrict__ w1a, const float* __restrict__ b1a,
    const float* __restrict__ w1b, const float* __restrict__ b1b,
    const float* __restrict__ w2,  const float* __restrict__ b2,
    const float* __restrict__ w3,  const float* __restrict__ b3,
    float* __restrict__ l_pre)
{
    float* xs    = sbuf;            // 3136
    float* y1s   = sbuf + 3136;     // 784
    float* pools = sbuf + 3920;     // 196
    const float* xp = x + ((size_t)(b * C_DIM + c)) * NPIX;
    for (int i = tid; i < NPIX / 4; i += 256)
        ((float4*)xs)[i] = ((const float4*)xp)[i];
    __syncthreads();

    const float wa0 = w1a[c*4+0], wa1 = w1a[c*4+1], wa2 = w1a[c*4+2], wa3 = w1a[c*4+3];
    const float ba = b1a[c];
    for (int i = tid; i < HWD * PW; i += 256) {
        int h = i / PW, w = i % PW;
        const float* r = xs + h * HWD + w * 4;
        float v = ba + r[0]*wa0 + r[1]*wa1 + r[2]*wa2 + r[3]*wa3;
        y1s[i] = fmaxf(v, 0.f);
    }
    if (tid < PP) {
        int h = tid / PW, w = tid % PW;
        float s = 0.f;
        #pragma unroll
        for (int r = 0; r < 4; ++r) {
            const float* rr = xs + (h*4 + r) * HWD + w * 4;
            s += rr[0] + rr[1] + rr[2] + rr[3];
        }
        pools[tid] = s * (1.f / 16.f);
    }
    __syncthreads();

    if (tid < PP) {
        int h = tid / PW, w = tid % PW;
        float* lp = l_pre + ((size_t)(b * C_DIM + c)) * M_TOT;
        float v1 = b1b[c];
        v1 += y1s[(h*4+0)*PW + w] * w1b[c*4+0];
        v1 += y1s[(h*4+1)*PW + w] * w1b[c*4+1];
        v1 += y1s[(h*4+2)*PW + w] * w1b[c*4+2];
        v1 += y1s[(h*4+3)*PW + w] * w1b[c*4+3];
        lp[tid] = fmaxf(v1, 0.f);
        float v2 = b2[c];
        #pragma unroll
        for (int r = 0; r < 4; ++r)
            #pragma unroll
            for (int s2 = 0; s2 < 4; ++s2)
                v2 += xs[(h*4+r)*HWD + w*4 + s2] * w2[c*16 + r*4 + s2];
        lp[PP + tid] = fmaxf(v2, 0.f);
        float v3 = b3[c];
        #pragma unroll
        for (int dh = -1; dh <= 1; ++dh)
            #pragma unroll
            for (int dw = -1; dw <= 1; ++dw) {
                int hh = h + dh, ww = w + dw;
                if (hh >= 0 && hh < PW && ww >= 0 && ww < PW)
                    v3 += pools[hh*PW + ww] * w3[c*9 + (dh+1)*3 + (dw+1)];
            }
        lp[2*PP + tid] = fmaxf(v3, 0.f);
    }
}

__device__ __forceinline__ void xpose_body(
    int bx, int by, int bz, int tid, float* sbuf,
    const float* __restrict__ x, short* __restrict__ Xb)
{
    float (*sx)[68] = (float(*)[68])sbuf;
    const int n0 = bx * 64, c0 = by * 64, b = bz;
    #pragma unroll
    for (int it = 0; it < 4; ++it) {
        int idx = tid + it * 256;
        int cr = idx >> 4, n4 = (idx & 15) * 4;
        float4 v = *(const float4*)(x + ((size_t)(b * C_DIM + c0 + cr)) * NPIX + n0 + n4);
        *(float4*)&sx[cr][n4] = v;
    }
    __syncthreads();
    #pragma unroll
    for (int p = 0; p < 2; ++p) {
        int idx = tid + p * 256;
        int nr = idx >> 3, cg = (idx & 7) * 8;
        short ov[8];
        #pragma unroll
        for (int e = 0; e < 8; ++e) ov[e] = f2bs(sx[cg + e][nr]);
        *(float4*)&Xb[((size_t)(b * NPIX + n0 + nr)) * C_DIM + c0 + cg] = *(float4*)ov;
    }
}

__device__ __forceinline__ void wconv_body(
    int blk, int tid,
    const float* __restrict__ Wq, const float* __restrict__ Wkv,
    short* __restrict__ Wqb, short* __restrict__ Wkvb)
{
    int i = (blk * 256 + tid) * 4;
    if (i < 262144) {
        float4 v = *(const float4*)(Wq + i);
        short o[4] = {f2bs(v.x), f2bs(v.y), f2bs(v.z), f2bs(v.w)};
        *(short4*)(Wqb + i) = *(short4*)o;
    } else {
        int j = i - 262144;
        float4 v = *(const float4*)(Wkv + j);
        short o[4] = {f2bs(v.x), f2bs(v.y), f2bs(v.z), f2bs(v.w)};
        *(short4*)(Wkvb + j) = *(short4*)o;
    }
}

__global__ __launch_bounds__(256) void k_front(
    const float* __restrict__ x,
    const float* __restrict__ Wq, const float* __restrict__ Wkv,
    short* __restrict__ Wqb, short* __restrict__ Wkvb,
    short* __restrict__ Xb,
    const float* __restrict__ w1a, const float* __restrict__ b1a,
    const float* __restrict__ w1b, const float* __restrict__ b1b,
    const float* __restrict__ w2,  const float* __restrict__ b2,
    const float* __restrict__ w3,  const float* __restrict__ b3,
    float* __restrict__ l_pre)
{
    __shared__ float sbuf[4368];   // max(branches 4116, xpose 4352)
    const int bid = blockIdx.x, tid = threadIdx.x;
    if (bid < 4096) {
        branches_body(bid & 511, bid >> 9, tid, sbuf,
                      x, w1a, b1a, w1b, b1b, w2, b2, w3, b3, l_pre);
    } else if (bid < 7232) {
        int i2 = bid - 4096;               // 3136 = 49*8*8
        xpose_body(i2 % 49, (i2 / 49) & 7, i2 / 392, tid, sbuf, x, Xb);
    } else {
        wconv_body(bid - 7232, tid, Wq, Wkv, Wqb, Wkvb);
    }
}

// ===========================================================================
// K2: fused mid — staged q-GEMM (m97 pattern, async gl_lds16) ∪ stats.
// (R5-measured config; R8's XCD remap was null and is reverted.)
// ===========================================================================

__device__ __forceinline__ void gemm_q_body(
    int bx, int by, int tid, short* As, short* Bs,
    const short* __restrict__ A, const short* __restrict__ Bw,
    const float* __restrict__ bias, short* __restrict__ Qb)
{
    const int lane = tid & 63, w = tid >> 6;
    const int l15 = lane & 15, quad = lane >> 4;
    const int wr = w & 1, wc = w >> 1;
    const int row0 = bx * 128, col0 = by * 128;
    const int lr8 = lane >> 3, lc8 = (lane & 7) * 8;

    f32x4 acc[4][4] = {};

    for (int c0 = 0; c0 < 512; c0 += 64) {
        __syncthreads();
        #pragma unroll
        for (int it = 0; it < 4; ++it) {
            int r = w * 32 + it * 8;
            gl_lds16(A  + (size_t)(row0 + r + lr8) * 512 + c0 + lc8, &As[r * 64]);
            gl_lds16(Bw + (size_t)(col0 + r + lr8) * 512 + c0 + lc8, &Bs[r * 64]);
        }
        __syncthreads();
        #pragma unroll
        for (int ks = 0; ks < 2; ++ks) {
            bf16x8 af[4], bf[4];
            #pragma unroll
            for (int t = 0; t < 4; ++t) {
                af[t] = *(const bf16x8*)&As[(wr*64 + t*16 + l15)*64 + ks*32 + quad*8];
                bf[t] = *(const bf16x8*)&Bs[(wc*64 + t*16 + l15)*64 + ks*32 + quad*8];
            }
            #pragma unroll
            for (int nt = 0; nt < 4; ++nt)
                #pragma unroll
                for (int mt = 0; mt < 4; ++mt)
                    acc[nt][mt] = __builtin_amdgcn_mfma_f32_16x16x32_bf16(
                        af[nt], bf[mt], acc[nt][mt], 0, 0, 0);
        }
    }

    #pragma unroll
    for (int nt = 0; nt < 4; ++nt) {
        int row_t = row0 + wr * 64 + nt * 16 + quad * 4;
        #pragma unroll
        for (int mt = 0; mt < 4; ++mt) {
            int col = col0 + wc * 64 + mt * 16 + l15;
            float bv = bias[col];
            int h = col >> 6, d = col & 63;
            #pragma unroll
            for (int r = 0; r < 4; ++r) {
                int row_g = row_t + r;
                int b = row_g / N_SEQ;
                int n = row_g - b * N_SEQ;
                Qb[(((size_t)(b * HEADS + h)) * N_SEQ + n) * HD + d] =
                    f2bs((acc[nt][mt][r] + bv) * SM_SCALE_LOG2E);
            }
        }
    }
}

__device__ __forceinline__ void stats_body(
    int sx_, int sb_, int tid, float* red,
    const float* __restrict__ l_pre, float2* __restrict__ stats)
{
    float* ssum = red;
    float* ssq  = red + 256;
    const int ml = tid & 63, cg = tid >> 6;
    const int b = sb_;
    const int m = sx_ * 64 + ml;
    float s = 0.f, q = 0.f;
    if (m < M_TOT) {
        const float* base = l_pre + ((size_t)b * C_DIM + cg * 128) * M_TOT + m;
        for (int c = 0; c < 128; ++c) {
            float v = base[(size_t)c * M_TOT];
            s += v; q += v * v;
        }
    }
    ssum[cg*64 + ml] = s; ssq[cg*64 + ml] = q;
    __syncthreads();
    if (tid < 64 && sx_ * 64 + tid < M_TOT) {
        float ts = ssum[tid] + ssum[64+tid] + ssum[128+tid] + ssum[192+tid];
        float tq = ssq[tid] + ssq[64+tid] + ssq[128+tid] + ssq[192+tid];
        float mu = ts * (1.f / 512.f);
        float var = tq * (1.f / 512.f) - mu * mu;
        stats[(size_t)b * M_TOT + sx_ * 64 + tid] =
            make_float2(mu, rsqrtf(var + 1e-5f));
    }
}

__global__ __launch_bounds__(256) void k_mid(
    const short* __restrict__ Xb, const short* __restrict__ Wqb,
    const float* __restrict__ bq, short* __restrict__ Qb,
    const float* __restrict__ l_pre, float2* __restrict__ stats)
{
    __shared__ short sb2[16384];   // gemm: As|Bs (32 KB); stats: 2 KB reduce
    const int bid = blockIdx.x, tid = threadIdx.x;
    if (bid < 784) {
        gemm_q_body(bid % 196, bid / 196, tid, sb2, sb2 + 8192,
                    Xb, Wqb, bq, Qb);
    } else {
        int sid = bid - 784;       // 80 = 10*8
        stats_body(sid % 10, sid / 10, tid, (float*)sb2, l_pre, stats);
    }
}

// ---------------------------------------------------------------------------
// Kernel L: LN(l_pre) transposed -> Lb [BM_PAD, C] bf16.
// ---------------------------------------------------------------------------
__global__ __launch_bounds__(256) void k_lnt(
    const float* __restrict__ l_pre, const float2* __restrict__ stats,
    const float* __restrict__ gamma, const float* __restrict__ beta,
    short* __restrict__ Lb)
{
    __shared__ float sx[64][68];
    const int tid = threadIdx.x;
    const int m0 = blockIdx.x * 64, c0 = blockIdx.y * 64, b = blockIdx.z;
    #pragma unroll
    for (int it = 0; it < 4; ++it) {
        int idx = tid + it * 256;
        int cr = idx >> 4, m4 = (idx & 15) * 4;
        float4 v = {0.f, 0.f, 0.f, 0.f};
        if (m0 + m4 < M_TOT)
            v = *(const float4*)(l_pre + ((size_t)(b * C_DIM + c0 + cr)) * M_TOT + m0 + m4);
        *(float4*)&sx[cr][m4] = v;
    }
    __syncthreads();
    #pragma unroll
    for (int p = 0; p < 2; ++p) {
        int idx = tid + p * 256;
        int mr = idx >> 3, cg = (idx & 7) * 8;
        int m = m0 + mr;
        float mu = 0.f, rstd = 0.f;
        if (m < M_TOT) {
            float2 st = stats[(size_t)b * M_TOT + m];
            mu = st.x; rstd = st.y;
        }
        short ov[8];
        #pragma unroll
        for (int e = 0; e < 8; ++e) {
            int c = c0 + cg + e;
            ov[e] = f2bs((sx[cg + e][mr] - mu) * rstd * gamma[c] + beta[c]);
        }
        if (m < M_TOT)
            *(float4*)&Lb[((size_t)(b * M_TOT + m)) * C_DIM + c0 + cg] = *(float4*)ov;
    }
}

// ---------------------------------------------------------------------------
// K4: kv GEMM (staged m97 pattern, R5 config).
// ---------------------------------------------------------------------------
__global__ __launch_bounds__(256) void k_gemm_kv(
    const short* __restrict__ A, const short* __restrict__ Bw,
    const float* __restrict__ bias,
    short* __restrict__ Kb, short* __restrict__ Vt)
{
    __shared__ short As[128 * 64];
    __shared__ short Bs[128 * 64];
    const int tid = threadIdx.x;
    const int lane = tid & 63, w = tid >> 6;
    const int l15 = lane & 15, quad = lane >> 4;
    const int wr = w & 1, wc = w >> 1;
    const int row0 = blockIdx.x * 128, col0 = blockIdx.y * 128;
    const int lr8 = lane >> 3, lc8 = (lane & 7) * 8;

    f32x4 acc[4][4] = {};

    for (int c0 = 0; c0 < 512; c0 += 64) {
        __syncthreads();
        #pragma unroll
        for (int it = 0; it < 4; ++it) {
            int r = w * 32 + it * 8;
            gl_lds16(A  + (size_t)(row0 + r + lr8) * 512 + c0 + lc8, &As[r * 64]);
            gl_lds16(Bw + (size_t)(col0 + r + lr8) * 512 + c0 + lc8, &Bs[r * 64]);
        }
        __syncthreads();
        #pragma unroll
        for (int ks = 0; ks < 2; ++ks) {
            bf16x8 af[4], bf[4];
            #pragma unroll
            for (int t = 0; t < 4; ++t) {
                af[t] = *(const bf16x8*)&As[(wr*64 + t*16 + l15)*64 + ks*32 + quad*8];
                bf[t] = *(const bf16x8*)&Bs[(wc*64 + t*16 + l15)*64 + ks*32 + quad*8];
            }
            #pragma unroll
            for (int nt = 0; nt < 4; ++nt)
                #pragma unroll
                for (int mt = 0; mt < 4; ++mt)
                    acc[nt][mt] = __builtin_amdgcn_mfma_f32_16x16x32_bf16(
                        af[nt], bf[mt], acc[nt][mt], 0, 0, 0);
        }
    }

    #pragma unroll
    for (int nt = 0; nt < 4; ++nt) {
        int row_t = row0 + wr * 64 + nt * 16 + quad * 4;
        #pragma unroll
        for (int mt = 0; mt < 4; ++mt) {
            int col = col0 + wc * 64 + mt * 16 + l15;
            float bv = bias[col];
            #pragma unroll
            for (int r = 0; r < 4; ++r) {
                int row_g = row_t + r;
                float v = acc[nt][mt][r] + bv;
                if (row_g < BM_ROWS) {
                    int b = row_g / M_TOT;
                    int m = row_g - b * M_TOT;
                    if (col < 512) {
                        int h = col >> 6, d = col & 63;
                        Kb[(((size_t)(b * HEADS + h)) * M_TOT + m) * HD + d] = f2bs(v);
                    } else {
                        int jj = col - 512, h = jj >> 6, d = jj & 63;
                        Vt[(((size_t)(b * HEADS + h)) * HD + d) * M_TOT + m] = f2bs(v);
                    }
                }
            }
        }
    }
}

// ---------------------------------------------------------------------------
// Kernel E: persistent-K MFMA attention, 2 blocks/CU.
// Grid = (8 n-splits, h, b) = 512 blocks, 1024 threads (16 waves).
// K (588x64 + pad) staged ONCE into 80.5 KB LDS -> TWO blocks co-resident
// per CU (32 waves/CU). V^T frags (8B/lane, shared across both strips) are
// read straight from global: the whole KV set is L3-resident and each
// block's V slice (75 KB) is L2-hot; the added latency is what the doubled
// TLP exists to hide (m114: co-resident waves overlap MFMA/VALU/mem pipes).
// Pad handling: K pad rows zeroed in LDS; pad P masked in the single tail
// step (quad==3 at j0=576), so rs needs no correction and V pad loads
// (masked) may read garbage safely.
// ---------------------------------------------------------------------------
__global__ __launch_bounds__(1024, 8) void k_attn(
    const short* __restrict__ Qb, const short* __restrict__ Kb,
    const short* __restrict__ Vt, float* __restrict__ out)
{
    extern __shared__ short smem[];
    short* Ks = smem;                       // [592][68]

    const int tid = threadIdx.x;
    const int lane = tid & 63, w = tid >> 6;
    const int l15 = lane & 15, quad = lane >> 4;
    const int q8 = blockIdx.x, h = blockIdx.y, b = blockIdx.z;
    const size_t bh = (size_t)(b * HEADS + h);
    const size_t kbase = bh * M_TOT * HD;          // Kb [B,h,M,d]
    const size_t vbase = bh * (size_t)HD * M_TOT;  // Vt [B,h,d,M]

    // ---- stage K: 588 rows x 64 d (4704 float4 over 1024 threads)
    for (int i = tid; i < 4704; i += 1024) {
        int row = i >> 3, seg = i & 7;
        *(float4*)&Ks[row * KS_STRIDE + seg * 8] =
            *(const float4*)(Kb + kbase + (size_t)row * 64 + seg * 8);
    }
    // K zero-pad rows 588..591 (cols 0..63)
    if (tid < 256) {
        int r = tid >> 6, cc = tid & 63;
        Ks[(588 + r) * KS_STRIDE + cc] = 0;
    }
    __syncthreads();   // the ONLY barrier

    if (w >= 13) return;   // waves 13..15: staging only

    const bf16x4 ones = {(short)0x3F80, (short)0x3F80, (short)0x3F80, (short)0x3F80};
    const float tmask = (quad == 3) ? 0.f : 1.f;

    // this wave's double-strip: rows rA..rA+15 (A) and +16 (B) of the
    // block's 392-row range. w==12: A half-valid (l15<8), B invalid.
    const int rA = w * 32 + l15;
    const int rB = rA + 16;
    int nA = q8 * QROWS_PER_BLK + rA; if (nA > N_SEQ - 1) nA = N_SEQ - 1;
    int nB = q8 * QROWS_PER_BLK + rB; if (nB > N_SEQ - 1) nB = N_SEQ - 1;
    const bool stA = (rA < QROWS_PER_BLK);
    const bool stB = (rB < QROWS_PER_BLK);

    bf16x8 qfA[2], qfB[2];
    #pragma unroll
    for (int ks = 0; ks < 2; ++ks) {
        qfA[ks] = *(const bf16x8*)(Qb + (bh * N_SEQ + nA) * HD + ks * 32 + quad * 8);
        qfB[ks] = *(const bf16x8*)(Qb + (bh * N_SEQ + nB) * HD + ks * 32 + quad * 8);
    }

    f32x4 oaccA[4] = {}, oaccB[4] = {};
    f32x4 rsaccA = {}, rsaccB = {};

    const short* vp0 = Vt + vbase + (size_t)l15 * M_TOT + quad * 4;

    auto STEP = [&](int j0, bool tail) {
        // V frags from global (L2-hot); issue first for slack before PV
        const short* vp = vp0 + j0;
        bf16x4 v0 = *(const bf16x4*)(vp);
        bf16x4 v1 = *(const bf16x4*)(vp + 16 * M_TOT);
        bf16x4 v2 = *(const bf16x4*)(vp + 32 * M_TOT);
        bf16x4 v3 = *(const bf16x4*)(vp + 48 * M_TOT);

        const short* kr = &Ks[(j0 + l15) * KS_STRIDE + quad * 8];
        bf16x8 kf0 = *(const bf16x8*)kr;
        bf16x8 kf1 = *(const bf16x8*)(kr + 32);

        f32x4 sA = {}, sB = {};
        sA = __builtin_amdgcn_mfma_f32_16x16x32_bf16(kf0, qfA[0], sA, 0, 0, 0);
        sB = __builtin_amdgcn_mfma_f32_16x16x32_bf16(kf0, qfB[0], sB, 0, 0, 0);
        sA = __builtin_amdgcn_mfma_f32_16x16x32_bf16(kf1, qfA[1], sA, 0, 0, 0);
        sB = __builtin_amdgcn_mfma_f32_16x16x32_bf16(kf1, qfB[1], sB, 0, 0, 0);

        float pA[4], pB[4];
        #pragma unroll
        for (int r = 0; r < 4; ++r) {
            pA[r] = fexp2(sA[r]);
            pB[r] = fexp2(sB[r]);
        }
        if (tail) {
            #pragma unroll
            for (int r = 0; r < 4; ++r) { pA[r] *= tmask; pB[r] *= tmask; }
        }
        unsigned ua[2] = {pkbf(pA[0], pA[1]), pkbf(pA[2], pA[3])};
        unsigned ub[2] = {pkbf(pB[0], pB[1]), pkbf(pB[2], pB[3])};
        bf16x4 pbA, pbB;
        __builtin_memcpy(&pbA, ua, 8);
        __builtin_memcpy(&pbB, ub, 8);

        // row-sum on the MFMA pipe (A=ones): every lane gets colsum(P)
        rsaccA = mfma16(ones, pbA, rsaccA);
        rsaccB = mfma16(ones, pbB, rsaccB);

        // PV: O^T[d][i] += V^T[d][j] P^T[j][i]
        oaccA[0] = mfma16(v0, pbA, oaccA[0]);
        oaccB[0] = mfma16(v0, pbB, oaccB[0]);
        oaccA[1] = mfma16(v1, pbA, oaccA[1]);
        oaccB[1] = mfma16(v1, pbB, oaccB[1]);
        oaccA[2] = mfma16(v2, pbA, oaccA[2]);
        oaccB[2] = mfma16(v2, pbB, oaccB[2]);
        oaccA[3] = mfma16(v3, pbA, oaccA[3]);
        oaccB[3] = mfma16(v3, pbB, oaccB[3]);
    };

    #pragma unroll 1
    for (int j0 = 0; j0 < 576; j0 += 16) STEP(j0, false);
    STEP(576, true);   // tail: pad P masked (no -4 correction needed)

    const float invA = 1.f / rsaccA[0];
    const float invB = 1.f / rsaccB[0];
    if (stA) {
        float* orowA = out + ((size_t)b * N_SEQ + nA) * C_DIM + h * HD;
        #pragma unroll
        for (int dt = 0; dt < 4; ++dt) {
            float4 o;
            o.x = oaccA[dt][0] * invA; o.y = oaccA[dt][1] * invA;
            o.z = oaccA[dt][2] * invA; o.w = oaccA[dt][3] * invA;
            *(float4*)&orowA[dt * 16 + quad * 4] = o;
        }
    }
    if (stB) {
        float* orowB = out + ((size_t)b * N_SEQ + nB) * C_DIM + h * HD;
        #pragma unroll
        for (int dt = 0; dt < 4; ++dt) {
            float4 o;
            o.x = oaccB[dt][0] * invB; o.y = oaccB[dt][1] * invB;
            o.z = oaccB[dt][2] * invB; o.w = oaccB[dt][3] * invB;
            *(float4*)&orowB[dt * 16 + quad * 4] = o;
        }
    }
}

// ---------------------------------------------------------------------------
// Workspace layout (R5-measured):
//   Xb    : ws + 0          (25,690,112)  — written K1, read K2
//   Wqb   : ws + 25,690,112 (   524,288)  — written K1, read K2
//   Wkvb  : ws + 26,214,400 ( 1,048,576)  — written K1, read K4
//   l_pre : ws + 27,262,976 ( 9,633,792)  — written K1, read K2/K3;
//   Kb/Vt :   same region                — written K4 (l_pre dead), read K5
//   Qb    : ws + 36,896,768 (25,690,112)  — written K2, read K5
// stats/Lb live in d_out (first 4.9 MB); consumed by K3/K4, then K5 (attn)
// overwrites every element of out.
// ---------------------------------------------------------------------------
extern "C" void kernel_launch(void* const* d_in, const int* in_sizes, int n_in,
                              void* d_out, int out_size, void* d_ws, size_t ws_size,
                              hipStream_t stream) {
    const float* x     = (const float*)d_in[0];
    const float* Wq    = (const float*)d_in[1];
    const float* bq    = (const float*)d_in[2];
    const float* Wkv   = (const float*)d_in[3];
    const float* bkv   = (const float*)d_in[4];
    const float* w1a   = (const float*)d_in[5];
    const float* b1a   = (const float*)d_in[6];
    const float* w1b   = (const float*)d_in[7];
    const float* b1b   = (const float*)d_in[8];
    const float* w2    = (const float*)d_in[9];
    const float* b2    = (const float*)d_in[10];
    const float* w3    = (const float*)d_in[11];
    const float* b3    = (const float*)d_in[12];
    const float* gamma = (const float*)d_in[13];
    const float* beta  = (const float*)d_in[14];
    float* out = (float*)d_out;

    char* ws = (char*)d_ws;
    short*  Xb    = (short*)ws;
    short*  Wqb   = (short*)(ws + 25690112);
    short*  Wkvb  = (short*)(ws + 26214400);
    float*  l_pre = (float*)(ws + 27262976);       // shares region with Kb/Vt
    short*  Kb    = (short*)(ws + 27262976);       // written after l_pre dead
    short*  Vt    = (short*)(ws + 32079872);
    short*  Qb    = (short*)(ws + 36896768);
    float2* stats = (float2*)d_out;                // 37,632 B in out-buffer
    short*  Lb    = (short*)((char*)d_out + 65536); // 4,849,664 B in out-buffer

    hipFuncSetAttribute((const void*)k_attn,
                        hipFuncAttributeMaxDynamicSharedMemorySize,
                        ATTN_LDS_BYTES);

    k_front<<<8000, 256, 0, stream>>>(
        x, Wq, Wkv, Wqb, Wkvb, Xb,
        w1a, b1a, w1b, b1b, w2, b2, w3, b3, l_pre);
    k_mid<<<864, 256, 0, stream>>>(Xb, Wqb, bq, Qb, l_pre, stats);
    k_lnt<<<dim3(10, 8, BATCH), 256, 0, stream>>>(l_pre, stats, gamma, beta, Lb);
    k_gemm_kv<<<dim3(37, 8), 256, 0, stream>>>(Lb, Wkvb, bkv, Kb, Vt);
    k_attn<<<dim3(8, HEADS, BATCH), 1024, ATTN_LDS_BYTES, stream>>>(Qb, Kb, Vt, out);
}

// Round 10
// 348.979 us; speedup vs baseline: 1.1107x; 1.1107x over previous
//
#include <hip/hip_runtime.h>
#include <hip/hip_bf16.h>

#define BATCH   8
#define C_DIM   512
#define HWD     56
#define NPIX    3136   // 56*56
#define PW      14
#define PP      196    // 14*14
#define M_TOT   588    // 3*196
#define BM_ROWS 4704   // 8*588
#define BM_PAD  4736   // padded to 37*128
#define HEADS   8
#define HD      64
#define N_SEQ   3136
#define SM_SCALE 0.125f
// SM_SCALE * log2(e): folded into Q at the q-GEMM epilogue, so the attention
// inner loop computes p = exp2(s) with NO multiply at all.
#define SM_SCALE_LOG2E 0.1803368801111204f

// attention LDS geometry — PHASE-STAGED: the 588-row j-range is processed in
// two staged phases so K AND V fit in 80.8 KB -> 2 blocks/CU (32 waves/CU).
// R9 proved the occupancy doubles at this footprint; R9's failure was V from
// global (scattered 8B reads -> 375MB HBM fetch). Here V stays in LDS with
// the proven coalesced staging, paid twice.
#define KS_STRIDE 68            // shorts per K row (34 words)
#define KROWS_P1  304           // phase-1 j rows (19 steps of 16)
#define VS_STRIDE 308           // shorts per V^T row per phase (154 words)
#define ATTN_LDS_SHORTS (KROWS_P1 * KS_STRIDE + 64 * VS_STRIDE)  // 40384
#define ATTN_LDS_BYTES  (ATTN_LDS_SHORTS * 2)                    // 80768
#define QROWS_PER_BLK 392       // 3136 / 8 n-splits

typedef __attribute__((ext_vector_type(8))) short bf16x8;
typedef __attribute__((ext_vector_type(4))) short bf16x4;
typedef __attribute__((ext_vector_type(4))) float f32x4;

__device__ __forceinline__ short f2bs(float f) {
    __hip_bfloat16 h = __float2bfloat16(f);
    return *reinterpret_cast<short*>(&h);
}
__device__ __forceinline__ unsigned pkbf(float lo, float hi) {
    __hip_bfloat162 t = __float22bfloat162_rn(make_float2(lo, hi));
    return *reinterpret_cast<unsigned*>(&t);
}
__device__ __forceinline__ float fexp2(float x) {
#if __has_builtin(__builtin_amdgcn_exp2f)
    return __builtin_amdgcn_exp2f(x);
#else
    return exp2f(x);
#endif
}

// 16x16x16 bf16 MFMA (K=16): B-operand layout k=quad*4+jj, n=l15 — matches
// the C/D layout of our S^T tiles directly (no transpose needed for PV).
__device__ __forceinline__ f32x4 mfma16(bf16x4 a, bf16x4 b, f32x4 c) {
#if __has_builtin(__builtin_amdgcn_mfma_f32_16x16x16bf16_1k)
    return __builtin_amdgcn_mfma_f32_16x16x16bf16_1k(a, b, c, 0, 0, 0);
#elif __has_builtin(__builtin_amdgcn_mfma_f32_16x16x16_bf16)
    return __builtin_amdgcn_mfma_f32_16x16x16_bf16(a, b, c, 0, 0, 0);
#else
    asm volatile("v_mfma_f32_16x16x16_bf16 %0, %1, %2, %0\n\ts_nop 7\n\ts_nop 1"
                 : "+v"(c) : "v"(a), "v"(b));
    return c;
#endif
}

// async 16B global->LDS copy (m97 pattern, wave-uniform LDS base).
__device__ __forceinline__ void gl_lds16(const void* g, void* l) {
    __builtin_amdgcn_global_load_lds(
        (const __attribute__((address_space(1))) void*)g,
        (__attribute__((address_space(3))) void*)l, 16, 0, 0);
}

// ===========================================================================
// K1: fused front-end — branches (4096) ∪ xpose (3136) ∪ wconv (768).
// ===========================================================================

__device__ __forceinline__ void branches_body(
    int c, int b, int tid, float* sbuf,
    const float* __restrict__ x,
    const float* __restrict__ w1a, const float* __restrict__ b1a,
    const float* __restrict__ w1b, const float* __restrict__ b1b,
    const float* __restrict__ w2,  const float* __restrict__ b2,
    const float* __restrict__ w3,  const float* __restrict__ b3,
    float* __restrict__ l_pre)
{
    float* xs    = sbuf;            // 3136
    float* y1s   = sbuf + 3136;     // 784
    float* pools = sbuf + 3920;     // 196
    const float* xp = x + ((size_t)(b * C_DIM + c)) * NPIX;
    for (int i = tid; i < NPIX / 4; i += 256)
        ((float4*)xs)[i] = ((const float4*)xp)[i];
    __syncthreads();

    const float wa0 = w1a[c*4+0], wa1 = w1a[c*4+1], wa2 = w1a[c*4+2], wa3 = w1a[c*4+3];
    const float ba = b1a[c];
    for (int i = tid; i < HWD * PW; i += 256) {
        int h = i / PW, w = i % PW;
        const float* r = xs + h * HWD + w * 4;
        float v = ba + r[0]*wa0 + r[1]*wa1 + r[2]*wa2 + r[3]*wa3;
        y1s[i] = fmaxf(v, 0.f);
    }
    if (tid < PP) {
        int h = tid / PW, w = tid % PW;
        float s = 0.f;
        #pragma unroll
        for (int r = 0; r < 4; ++r) {
            const float* rr = xs + (h*4 + r) * HWD + w * 4;
            s += rr[0] + rr[1] + rr[2] + rr[3];
        }
        pools[tid] = s * (1.f / 16.f);
    }
    __syncthreads();

    if (tid < PP) {
        int h = tid / PW, w = tid % PW;
        float* lp = l_pre + ((size_t)(b * C_DIM + c)) * M_TOT;
        float v1 = b1b[c];
        v1 += y1s[(h*4+0)*PW + w] * w1b[c*4+0];
        v1 += y1s[(h*4+1)*PW + w] * w1b[c*4+1];
        v1 += y1s[(h*4+2)*PW + w] * w1b[c*4+2];
        v1 += y1s[(h*4+3)*PW + w] * w1b[c*4+3];
        lp[tid] = fmaxf(v1, 0.f);
        float v2 = b2[c];
        #pragma unroll
        for (int r = 0; r < 4; ++r)
            #pragma unroll
            for (int s2 = 0; s2 < 4; ++s2)
                v2 += xs[(h*4+r)*HWD + w*4 + s2] * w2[c*16 + r*4 + s2];
        lp[PP + tid] = fmaxf(v2, 0.f);
        float v3 = b3[c];
        #pragma unroll
        for (int dh = -1; dh <= 1; ++dh)
            #pragma unroll
            for (int dw = -1; dw <= 1; ++dw) {
                int hh = h + dh, ww = w + dw;
                if (hh >= 0 && hh < PW && ww >= 0 && ww < PW)
                    v3 += pools[hh*PW + ww] * w3[c*9 + (dh+1)*3 + (dw+1)];
            }
        lp[2*PP + tid] = fmaxf(v3, 0.f);
    }
}

__device__ __forceinline__ void xpose_body(
    int bx, int by, int bz, int tid, float* sbuf,
    const float* __restrict__ x, short* __restrict__ Xb)
{
    float (*sx)[68] = (float(*)[68])sbuf;
    const int n0 = bx * 64, c0 = by * 64, b = bz;
    #pragma unroll
    for (int it = 0; it < 4; ++it) {
        int idx = tid + it * 256;
        int cr = idx >> 4, n4 = (idx & 15) * 4;
        float4 v = *(const float4*)(x + ((size_t)(b * C_DIM + c0 + cr)) * NPIX + n0 + n4);
        *(float4*)&sx[cr][n4] = v;
    }
    __syncthreads();
    #pragma unroll
    for (int p = 0; p < 2; ++p) {
        int idx = tid + p * 256;
        int nr = idx >> 3, cg = (idx & 7) * 8;
        short ov[8];
        #pragma unroll
        for (int e = 0; e < 8; ++e) ov[e] = f2bs(sx[cg + e][nr]);
        *(float4*)&Xb[((size_t)(b * NPIX + n0 + nr)) * C_DIM + c0 + cg] = *(float4*)ov;
    }
}

__device__ __forceinline__ void wconv_body(
    int blk, int tid,
    const float* __restrict__ Wq, const float* __restrict__ Wkv,
    short* __restrict__ Wqb, short* __restrict__ Wkvb)
{
    int i = (blk * 256 + tid) * 4;
    if (i < 262144) {
        float4 v = *(const float4*)(Wq + i);
        short o[4] = {f2bs(v.x), f2bs(v.y), f2bs(v.z), f2bs(v.w)};
        *(short4*)(Wqb + i) = *(short4*)o;
    } else {
        int j = i - 262144;
        float4 v = *(const float4*)(Wkv + j);
        short o[4] = {f2bs(v.x), f2bs(v.y), f2bs(v.z), f2bs(v.w)};
        *(short4*)(Wkvb + j) = *(short4*)o;
    }
}

__global__ __launch_bounds__(256) void k_front(
    const float* __restrict__ x,
    const float* __restrict__ Wq, const float* __restrict__ Wkv,
    short* __restrict__ Wqb, short* __restrict__ Wkvb,
    short* __restrict__ Xb,
    const float* __restrict__ w1a, const float* __restrict__ b1a,
    const float* __restrict__ w1b, const float* __restrict__ b1b,
    const float* __restrict__ w2,  const float* __restrict__ b2,
    const float* __restrict__ w3,  const float* __restrict__ b3,
    float* __restrict__ l_pre)
{
    __shared__ float sbuf[4368];   // max(branches 4116, xpose 4352)
    const int bid = blockIdx.x, tid = threadIdx.x;
    if (bid < 4096) {
        branches_body(bid & 511, bid >> 9, tid, sbuf,
                      x, w1a, b1a, w1b, b1b, w2, b2, w3, b3, l_pre);
    } else if (bid < 7232) {
        int i2 = bid - 4096;               // 3136 = 49*8*8
        xpose_body(i2 % 49, (i2 / 49) & 7, i2 / 392, tid, sbuf, x, Xb);
    } else {
        wconv_body(bid - 7232, tid, Wq, Wkv, Wqb, Wkvb);
    }
}

// ===========================================================================
// K2: fused mid — staged q-GEMM (m97 pattern, async gl_lds16) ∪ stats.
// (exact R5 config — XCD remap was null in R8 and is reverted)
// ===========================================================================

__device__ __forceinline__ void gemm_q_body(
    int bx, int by, int tid, short* As, short* Bs,
    const short* __restrict__ A, const short* __restrict__ Bw,
    const float* __restrict__ bias, short* __restrict__ Qb)
{
    const int lane = tid & 63, w = tid >> 6;
    const int l15 = lane & 15, quad = lane >> 4;
    const int wr = w & 1, wc = w >> 1;
    const int row0 = bx * 128, col0 = by * 128;
    const int lr8 = lane >> 3, lc8 = (lane & 7) * 8;

    f32x4 acc[4][4] = {};

    for (int c0 = 0; c0 < 512; c0 += 64) {
        __syncthreads();
        #pragma unroll
        for (int it = 0; it < 4; ++it) {
            int r = w * 32 + it * 8;
            gl_lds16(A  + (size_t)(row0 + r + lr8) * 512 + c0 + lc8, &As[r * 64]);
            gl_lds16(Bw + (size_t)(col0 + r + lr8) * 512 + c0 + lc8, &Bs[r * 64]);
        }
        __syncthreads();
        #pragma unroll
        for (int ks = 0; ks < 2; ++ks) {
            bf16x8 af[4], bf[4];
            #pragma unroll
            for (int t = 0; t < 4; ++t) {
                af[t] = *(const bf16x8*)&As[(wr*64 + t*16 + l15)*64 + ks*32 + quad*8];
                bf[t] = *(const bf16x8*)&Bs[(wc*64 + t*16 + l15)*64 + ks*32 + quad*8];
            }
            #pragma unroll
            for (int nt = 0; nt < 4; ++nt)
                #pragma unroll
                for (int mt = 0; mt < 4; ++mt)
                    acc[nt][mt] = __builtin_amdgcn_mfma_f32_16x16x32_bf16(
                        af[nt], bf[mt], acc[nt][mt], 0, 0, 0);
        }
    }

    #pragma unroll
    for (int nt = 0; nt < 4; ++nt) {
        int row_t = row0 + wr * 64 + nt * 16 + quad * 4;
        #pragma unroll
        for (int mt = 0; mt < 4; ++mt) {
            int col = col0 + wc * 64 + mt * 16 + l15;
            float bv = bias[col];
            int h = col >> 6, d = col & 63;
            #pragma unroll
            for (int r = 0; r < 4; ++r) {
                int row_g = row_t + r;
                int b = row_g / N_SEQ;
                int n = row_g - b * N_SEQ;
                Qb[(((size_t)(b * HEADS + h)) * N_SEQ + n) * HD + d] =
                    f2bs((acc[nt][mt][r] + bv) * SM_SCALE_LOG2E);
            }
        }
    }
}

__device__ __forceinline__ void stats_body(
    int sx_, int sb_, int tid, float* red,
    const float* __restrict__ l_pre, float2* __restrict__ stats)
{
    float* ssum = red;
    float* ssq  = red + 256;
    const int ml = tid & 63, cg = tid >> 6;
    const int b = sb_;
    const int m = sx_ * 64 + ml;
    float s = 0.f, q = 0.f;
    if (m < M_TOT) {
        const float* base = l_pre + ((size_t)b * C_DIM + cg * 128) * M_TOT + m;
        for (int c = 0; c < 128; ++c) {
            float v = base[(size_t)c * M_TOT];
            s += v; q += v * v;
        }
    }
    ssum[cg*64 + ml] = s; ssq[cg*64 + ml] = q;
    __syncthreads();
    if (tid < 64 && sx_ * 64 + tid < M_TOT) {
        float ts = ssum[tid] + ssum[64+tid] + ssum[128+tid] + ssum[192+tid];
        float tq = ssq[tid] + ssq[64+tid] + ssq[128+tid] + ssq[192+tid];
        float mu = ts * (1.f / 512.f);
        float var = tq * (1.f / 512.f) - mu * mu;
        stats[(size_t)b * M_TOT + sx_ * 64 + tid] =
            make_float2(mu, rsqrtf(var + 1e-5f));
    }
}

__global__ __launch_bounds__(256) void k_mid(
    const short* __restrict__ Xb, const short* __restrict__ Wqb,
    const float* __restrict__ bq, short* __restrict__ Qb,
    const float* __restrict__ l_pre, float2* __restrict__ stats)
{
    __shared__ short sb2[16384];   // gemm: As|Bs (32 KB); stats: 2 KB reduce
    const int bid = blockIdx.x, tid = threadIdx.x;
    if (bid < 784) {
        gemm_q_body(bid % 196, bid / 196, tid, sb2, sb2 + 8192,
                    Xb, Wqb, bq, Qb);
    } else {
        int sid = bid - 784;       // 80 = 10*8
        stats_body(sid % 10, sid / 10, tid, (float*)sb2, l_pre, stats);
    }
}

// ---------------------------------------------------------------------------
// Kernel L: LN(l_pre) transposed -> Lb [BM_PAD, C] bf16.
// ---------------------------------------------------------------------------
__global__ __launch_bounds__(256) void k_lnt(
    const float* __restrict__ l_pre, const float2* __restrict__ stats,
    const float* __restrict__ gamma, const float* __restrict__ beta,
    short* __restrict__ Lb)
{
    __shared__ float sx[64][68];
    const int tid = threadIdx.x;
    const int m0 = blockIdx.x * 64, c0 = blockIdx.y * 64, b = blockIdx.z;
    #pragma unroll
    for (int it = 0; it < 4; ++it) {
        int idx = tid + it * 256;
        int cr = idx >> 4, m4 = (idx & 15) * 4;
        float4 v = {0.f, 0.f, 0.f, 0.f};
        if (m0 + m4 < M_TOT)
            v = *(const float4*)(l_pre + ((size_t)(b * C_DIM + c0 + cr)) * M_TOT + m0 + m4);
        *(float4*)&sx[cr][m4] = v;
    }
    __syncthreads();
    #pragma unroll
    for (int p = 0; p < 2; ++p) {
        int idx = tid + p * 256;
        int mr = idx >> 3, cg = (idx & 7) * 8;
        int m = m0 + mr;
        float mu = 0.f, rstd = 0.f;
        if (m < M_TOT) {
            float2 st = stats[(size_t)b * M_TOT + m];
            mu = st.x; rstd = st.y;
        }
        short ov[8];
        #pragma unroll
        for (int e = 0; e < 8; ++e) {
            int c = c0 + cg + e;
            ov[e] = f2bs((sx[cg + e][mr] - mu) * rstd * gamma[c] + beta[c]);
        }
        if (m < M_TOT)
            *(float4*)&Lb[((size_t)(b * M_TOT + m)) * C_DIM + c0 + cg] = *(float4*)ov;
    }
}

// ---------------------------------------------------------------------------
// K4: kv GEMM (staged m97 pattern, exact R5 config).
// ---------------------------------------------------------------------------
__global__ __launch_bounds__(256) void k_gemm_kv(
    const short* __restrict__ A, const short* __restrict__ Bw,
    const float* __restrict__ bias,
    short* __restrict__ Kb, short* __restrict__ Vt)
{
    __shared__ short As[128 * 64];
    __shared__ short Bs[128 * 64];
    const int tid = threadIdx.x;
    const int lane = tid & 63, w = tid >> 6;
    const int l15 = lane & 15, quad = lane >> 4;
    const int wr = w & 1, wc = w >> 1;
    const int row0 = blockIdx.x * 128, col0 = blockIdx.y * 128;
    const int lr8 = lane >> 3, lc8 = (lane & 7) * 8;

    f32x4 acc[4][4] = {};

    for (int c0 = 0; c0 < 512; c0 += 64) {
        __syncthreads();
        #pragma unroll
        for (int it = 0; it < 4; ++it) {
            int r = w * 32 + it * 8;
            gl_lds16(A  + (size_t)(row0 + r + lr8) * 512 + c0 + lc8, &As[r * 64]);
            gl_lds16(Bw + (size_t)(col0 + r + lr8) * 512 + c0 + lc8, &Bs[r * 64]);
        }
        __syncthreads();
        #pragma unroll
        for (int ks = 0; ks < 2; ++ks) {
            bf16x8 af[4], bf[4];
            #pragma unroll
            for (int t = 0; t < 4; ++t) {
                af[t] = *(const bf16x8*)&As[(wr*64 + t*16 + l15)*64 + ks*32 + quad*8];
                bf[t] = *(const bf16x8*)&Bs[(wc*64 + t*16 + l15)*64 + ks*32 + quad*8];
            }
            #pragma unroll
            for (int nt = 0; nt < 4; ++nt)
                #pragma unroll
                for (int mt = 0; mt < 4; ++mt)
                    acc[nt][mt] = __builtin_amdgcn_mfma_f32_16x16x32_bf16(
                        af[nt], bf[mt], acc[nt][mt], 0, 0, 0);
        }
    }

    #pragma unroll
    for (int nt = 0; nt < 4; ++nt) {
        int row_t = row0 + wr * 64 + nt * 16 + quad * 4;
        #pragma unroll
        for (int mt = 0; mt < 4; ++mt) {
            int col = col0 + wc * 64 + mt * 16 + l15;
            float bv = bias[col];
            #pragma unroll
            for (int r = 0; r < 4; ++r) {
                int row_g = row_t + r;
                float v = acc[nt][mt][r] + bv;
                if (row_g < BM_ROWS) {
                    int b = row_g / M_TOT;
                    int m = row_g - b * M_TOT;
                    if (col < 512) {
                        int h = col >> 6, d = col & 63;
                        Kb[(((size_t)(b * HEADS + h)) * M_TOT + m) * HD + d] = f2bs(v);
                    } else {
                        int jj = col - 512, h = jj >> 6, d = jj & 63;
                        Vt[(((size_t)(b * HEADS + h)) * HD + d) * M_TOT + m] = f2bs(v);
                    }
                }
            }
        }
    }
}

// ---------------------------------------------------------------------------
// Kernel E: phase-staged persistent-KV MFMA attention, 2 blocks/CU.
// Grid = (8 n-splits, h, b) = 512 blocks, 1024 threads (16 waves).
// LDS 80.8 KB/block (K[304][68] + V^T[64][308]) -> 2 blocks/CU, 32 waves/CU.
// j-range split: phase 1 = j 0..303 (19 steps), phase 2 = j 304..587
// (17.75 steps: 18 staged steps with 4 zeroed pad rows; pad P masked at
// quad==3 of the final step, so rs needs no correction and 0*pad is exact).
// Waves 13..15 only stage; all waves join the phase barriers.
// ---------------------------------------------------------------------------
__global__ __launch_bounds__(1024, 8) void k_attn(
    const short* __restrict__ Qb, const short* __restrict__ Kb,
    const short* __restrict__ Vt, float* __restrict__ out)
{
    extern __shared__ short smem[];
    short* Ks = smem;                        // [304][68]
    short* Vs = smem + KROWS_P1 * KS_STRIDE; // [64][308]

    const int tid = threadIdx.x;
    const int lane = tid & 63, w = tid >> 6;
    const int l15 = lane & 15, quad = lane >> 4;
    const int q8 = blockIdx.x, h = blockIdx.y, b = blockIdx.z;
    const size_t bh = (size_t)(b * HEADS + h);
    const size_t kbase = bh * M_TOT * HD;          // Kb [B,h,M,d]
    const size_t vbase = bh * (size_t)HD * M_TOT;  // Vt [B,h,d,M]

    // this wave's double-strip: rows rA (A) and rA+16 (B) of the block's
    // 392-row range; w==12 is half-valid, clamped rows compute-waste only.
    const int rA = w * 32 + l15;
    const int rB = rA + 16;
    int nA = q8 * QROWS_PER_BLK + rA; if (nA > N_SEQ - 1) nA = N_SEQ - 1;
    int nB = q8 * QROWS_PER_BLK + rB; if (nB > N_SEQ - 1) nB = N_SEQ - 1;
    const bool stA = (rA < QROWS_PER_BLK);
    const bool stB = (rB < QROWS_PER_BLK);
    const bool cw = (w < 13);                // compute wave

    bf16x8 qfA[2], qfB[2];
    #pragma unroll
    for (int ks = 0; ks < 2; ++ks) {
        qfA[ks] = *(const bf16x8*)(Qb + (bh * N_SEQ + nA) * HD + ks * 32 + quad * 8);
        qfB[ks] = *(const bf16x8*)(Qb + (bh * N_SEQ + nB) * HD + ks * 32 + quad * 8);
    }

    f32x4 oaccA[4] = {}, oaccB[4] = {};
    f32x4 rsaccA = {}, rsaccB = {};
    const bf16x4 ones = {(short)0x3F80, (short)0x3F80, (short)0x3F80, (short)0x3F80};
    const float tmask = (quad == 3) ? 0.f : 1.f;

    auto STAGE = [&](int jb, int rows, bool pad) {
        // K: rows x 64d, float4-coalesced
        for (int i = tid; i < rows * 8; i += 1024) {
            int row = i >> 3, seg = i & 7;
            *(float4*)&Ks[row * KS_STRIDE + seg * 8] =
                *(const float4*)(Kb + kbase + (size_t)(jb + row) * 64 + seg * 8);
        }
        // V^T: 64 d-rows x rows j-cols, float2-coalesced (16 thr/row)
        {
            int row = tid >> 4, tg = tid & 15;
            const short* src = Vt + vbase + (size_t)row * M_TOT + jb;
            for (int jj = tg; jj < rows / 4; jj += 16)
                *(float2*)&Vs[row * VS_STRIDE + jj * 4] = *(const float2*)(src + jj * 4);
        }
        if (pad) {
            if (tid < 256) {                 // K pad rows 284..287
                int r = tid >> 6, cc = tid & 63;
                Ks[(284 + r) * KS_STRIDE + cc] = 0;
            } else if (tid < 512) {          // V pad cols 284..287
                int idx = tid - 256;
                int row = idx >> 2, cc = idx & 3;
                Vs[row * VS_STRIDE + 284 + cc] = 0;
            }
        }
    };

    auto STEP = [&](int j0, bool tail) {
        const short* kr = &Ks[(j0 + l15) * KS_STRIDE + quad * 8];
        bf16x8 kf0 = *(const bf16x8*)kr;
        bf16x8 kf1 = *(const bf16x8*)(kr + 32);
        const short* vr = &Vs[l15 * VS_STRIDE + j0 + quad * 4];
        bf16x4 v0 = *(const bf16x4*)vr;
        bf16x4 v1 = *(const bf16x4*)(vr + 16 * VS_STRIDE);
        bf16x4 v2 = *(const bf16x4*)(vr + 32 * VS_STRIDE);
        bf16x4 v3 = *(const bf16x4*)(vr + 48 * VS_STRIDE);

        f32x4 sA = {}, sB = {};
        sA = __builtin_amdgcn_mfma_f32_16x16x32_bf16(kf0, qfA[0], sA, 0, 0, 0);
        sB = __builtin_amdgcn_mfma_f32_16x16x32_bf16(kf0, qfB[0], sB, 0, 0, 0);
        sA = __builtin_amdgcn_mfma_f32_16x16x32_bf16(kf1, qfA[1], sA, 0, 0, 0);
        sB = __builtin_amdgcn_mfma_f32_16x16x32_bf16(kf1, qfB[1], sB, 0, 0, 0);

        float pA[4], pB[4];
        #pragma unroll
        for (int r = 0; r < 4; ++r) {
            pA[r] = fexp2(sA[r]);
            pB[r] = fexp2(sB[r]);
        }
        if (tail) {
            #pragma unroll
            for (int r = 0; r < 4; ++r) { pA[r] *= tmask; pB[r] *= tmask; }
        }
        unsigned ua[2] = {pkbf(pA[0], pA[1]), pkbf(pA[2], pA[3])};
        unsigned ub[2] = {pkbf(pB[0], pB[1]), pkbf(pB[2], pB[3])};
        bf16x4 pbA, pbB;
        __builtin_memcpy(&pbA, ua, 8);
        __builtin_memcpy(&pbB, ub, 8);

        rsaccA = mfma16(ones, pbA, rsaccA);
        rsaccB = mfma16(ones, pbB, rsaccB);

        oaccA[0] = mfma16(v0, pbA, oaccA[0]);
        oaccB[0] = mfma16(v0, pbB, oaccB[0]);
        oaccA[1] = mfma16(v1, pbA, oaccA[1]);
        oaccB[1] = mfma16(v1, pbB, oaccB[1]);
        oaccA[2] = mfma16(v2, pbA, oaccA[2]);
        oaccB[2] = mfma16(v2, pbB, oaccB[2]);
        oaccA[3] = mfma16(v3, pbA, oaccA[3]);
        oaccB[3] = mfma16(v3, pbB, oaccB[3]);
    };

    // ---- phase 1: j in [0, 304)
    STAGE(0, 304, false);
    __syncthreads();
    if (cw) {
        #pragma unroll 1
        for (int j0 = 0; j0 < 304; j0 += 16) STEP(j0, false);
    }
    __syncthreads();   // all waves: computes done before re-stage

    // ---- phase 2: j in [304, 588) + 4 pad rows
    STAGE(304, 284, true);
    __syncthreads();
    if (cw) {
        #pragma unroll 1
        for (int j0 = 0; j0 < 272; j0 += 16) STEP(j0, false);
        STEP(272, true);   // pad rows 284..287 masked via quad==3

        const float invA = 1.f / rsaccA[0];
        const float invB = 1.f / rsaccB[0];
        if (stA) {
            float* orowA = out + ((size_t)b * N_SEQ + nA) * C_DIM + h * HD;
            #pragma unroll
            for (int dt = 0; dt < 4; ++dt) {
                float4 o;
                o.x = oaccA[dt][0] * invA; o.y = oaccA[dt][1] * invA;
                o.z = oaccA[dt][2] * invA; o.w = oaccA[dt][3] * invA;
                *(float4*)&orowA[dt * 16 + quad * 4] = o;
            }
        }
        if (stB) {
            float* orowB = out + ((size_t)b * N_SEQ + nB) * C_DIM + h * HD;
            #pragma unroll
            for (int dt = 0; dt < 4; ++dt) {
                float4 o;
                o.x = oaccB[dt][0] * invB; o.y = oaccB[dt][1] * invB;
                o.z = oaccB[dt][2] * invB; o.w = oaccB[dt][3] * invB;
                *(float4*)&orowB[dt * 16 + quad * 4] = o;
            }
        }
    }
}

// ---------------------------------------------------------------------------
// Workspace layout (R5-measured):
//   Xb    : ws + 0          (25,690,112)  — written K1, read K2
//   Wqb   : ws + 25,690,112 (   524,288)  — written K1, read K2
//   Wkvb  : ws + 26,214,400 ( 1,048,576)  — written K1, read K4
//   l_pre : ws + 27,262,976 ( 9,633,792)  — written K1, read K2/K3;
//   Kb/Vt :   same region                — written K4 (l_pre dead), read K5
//   Qb    : ws + 36,896,768 (25,690,112)  — written K2, read K5
// stats/Lb live in d_out (first 4.9 MB); consumed by K3/K4, then K5 (attn)
// overwrites every element of out.
// ---------------------------------------------------------------------------
extern "C" void kernel_launch(void* const* d_in, const int* in_sizes, int n_in,
                              void* d_out, int out_size, void* d_ws, size_t ws_size,
                              hipStream_t stream) {
    const float* x     = (const float*)d_in[0];
    const float* Wq    = (const float*)d_in[1];
    const float* bq    = (const float*)d_in[2];
    const float* Wkv   = (const float*)d_in[3];
    const float* bkv   = (const float*)d_in[4];
    const float* w1a   = (const float*)d_in[5];
    const float* b1a   = (const float*)d_in[6];
    const float* w1b   = (const float*)d_in[7];
    const float* b1b   = (const float*)d_in[8];
    const float* w2    = (const float*)d_in[9];
    const float* b2    = (const float*)d_in[10];
    const float* w3    = (const float*)d_in[11];
    const float* b3    = (const float*)d_in[12];
    const float* gamma = (const float*)d_in[13];
    const float* beta  = (const float*)d_in[14];
    float* out = (float*)d_out;

    char* ws = (char*)d_ws;
    short*  Xb    = (short*)ws;
    short*  Wqb   = (short*)(ws + 25690112);
    short*  Wkvb  = (short*)(ws + 26214400);
    float*  l_pre = (float*)(ws + 27262976);       // shares region with Kb/Vt
    short*  Kb    = (short*)(ws + 27262976);       // written after l_pre dead
    short*  Vt    = (short*)(ws + 32079872);
    short*  Qb    = (short*)(ws + 36896768);
    float2* stats = (float2*)d_out;                // 37,632 B in out-buffer
    short*  Lb    = (short*)((char*)d_out + 65536); // 4,849,664 B in out-buffer

    hipFuncSetAttribute((const void*)k_attn,
                        hipFuncAttributeMaxDynamicSharedMemorySize,
                        ATTN_LDS_BYTES);

    k_front<<<8000, 256, 0, stream>>>(
        x, Wq, Wkv, Wqb, Wkvb, Xb,
        w1a, b1a, w1b, b1b, w2, b2, w3, b3, l_pre);
    k_mid<<<864, 256, 0, stream>>>(Xb, Wqb, bq, Qb, l_pre, stats);
    k_lnt<<<dim3(10, 8, BATCH), 256, 0, stream>>>(l_pre, stats, gamma, beta, Lb);
    k_gemm_kv<<<dim3(37, 8), 256, 0, stream>>>(Lb, Wkvb, bkv, Kb, Vt);
    k_attn<<<dim3(8, HEADS, BATCH), 1024, ATTN_LDS_BYTES, stream>>>(Qb, Kb, Vt, out);
}

// Round 11
// 332.077 us; speedup vs baseline: 1.1673x; 1.0509x over previous
//
#include <hip/hip_runtime.h>
#include <hip/hip_bf16.h>

#define BATCH   8
#define C_DIM   512
#define HWD     56
#define NPIX    3136   // 56*56
#define PW      14
#define PP      196    // 14*14
#define M_TOT   588    // 3*196
#define BM_ROWS 4704   // 8*588
#define BM_PAD  4736   // padded to 37*128
#define HEADS   8
#define HD      64
#define N_SEQ   3136
#define SM_SCALE 0.125f
// SM_SCALE * log2(e): folded into Q at the q-GEMM epilogue, so the attention
// inner loop computes p = exp2(s) with NO multiply at all.
#define SM_SCALE_LOG2E 0.1803368801111204f

// attention LDS geometry — PHASE-STAGED K+V, 80.8 KB -> 2 blocks/CU possible.
// R9/R10 lesson: __launch_bounds__(1024,8) capped regs at ~64 TOTAL and the
// double-strip body (~90 regs) spilled to scratch (VGPR=32, +100MB HBM).
// This revision: SINGLE-strip waves (~52 regs) + no forced waves-per-eu —
// if the body fits <=64 the HW co-schedules 2 blocks/CU on its own.
#define KS_STRIDE 68            // shorts per K row (34 words)
#define KROWS_P1  304           // phase-1 j rows (19 steps of 16)
#define VS_STRIDE 308           // shorts per V^T row per phase (154 words)
#define ATTN_LDS_SHORTS (KROWS_P1 * KS_STRIDE + 64 * VS_STRIDE)  // 40384
#define ATTN_LDS_BYTES  (ATTN_LDS_SHORTS * 2)                    // 80768
#define NSPLIT  14
#define QROWS_PER_BLK 224       // 3136 / 14 — 14 waves x 16 rows, exact

typedef __attribute__((ext_vector_type(8))) short bf16x8;
typedef __attribute__((ext_vector_type(4))) short bf16x4;
typedef __attribute__((ext_vector_type(4))) float f32x4;

__device__ __forceinline__ short f2bs(float f) {
    __hip_bfloat16 h = __float2bfloat16(f);
    return *reinterpret_cast<short*>(&h);
}
__device__ __forceinline__ unsigned pkbf(float lo, float hi) {
    __hip_bfloat162 t = __float22bfloat162_rn(make_float2(lo, hi));
    return *reinterpret_cast<unsigned*>(&t);
}
__device__ __forceinline__ float fexp2(float x) {
#if __has_builtin(__builtin_amdgcn_exp2f)
    return __builtin_amdgcn_exp2f(x);
#else
    return exp2f(x);
#endif
}

// 16x16x16 bf16 MFMA (K=16): B-operand layout k=quad*4+jj, n=l15 — matches
// the C/D layout of our S^T tiles directly (no transpose needed for PV).
__device__ __forceinline__ f32x4 mfma16(bf16x4 a, bf16x4 b, f32x4 c) {
#if __has_builtin(__builtin_amdgcn_mfma_f32_16x16x16bf16_1k)
    return __builtin_amdgcn_mfma_f32_16x16x16bf16_1k(a, b, c, 0, 0, 0);
#elif __has_builtin(__builtin_amdgcn_mfma_f32_16x16x16_bf16)
    return __builtin_amdgcn_mfma_f32_16x16x16_bf16(a, b, c, 0, 0, 0);
#else
    asm volatile("v_mfma_f32_16x16x16_bf16 %0, %1, %2, %0\n\ts_nop 7\n\ts_nop 1"
                 : "+v"(c) : "v"(a), "v"(b));
    return c;
#endif
}

// async 16B global->LDS copy (m97 pattern, wave-uniform LDS base).
__device__ __forceinline__ void gl_lds16(const void* g, void* l) {
    __builtin_amdgcn_global_load_lds(
        (const __attribute__((address_space(1))) void*)g,
        (__attribute__((address_space(3))) void*)l, 16, 0, 0);
}

// ===========================================================================
// K1: fused front-end — branches (4096) ∪ xpose (3136) ∪ wconv (768).
// ===========================================================================

__device__ __forceinline__ void branches_body(
    int c, int b, int tid, float* sbuf,
    const float* __restrict__ x,
    const float* __restrict__ w1a, const float* __restrict__ b1a,
    const float* __restrict__ w1b, const float* __restrict__ b1b,
    const float* __restrict__ w2,  const float* __restrict__ b2,
    const float* __restrict__ w3,  const float* __restrict__ b3,
    float* __restrict__ l_pre)
{
    float* xs    = sbuf;            // 3136
    float* y1s   = sbuf + 3136;     // 784
    float* pools = sbuf + 3920;     // 196
    const float* xp = x + ((size_t)(b * C_DIM + c)) * NPIX;
    for (int i = tid; i < NPIX / 4; i += 256)
        ((float4*)xs)[i] = ((const float4*)xp)[i];
    __syncthreads();

    const float wa0 = w1a[c*4+0], wa1 = w1a[c*4+1], wa2 = w1a[c*4+2], wa3 = w1a[c*4+3];
    const float ba = b1a[c];
    for (int i = tid; i < HWD * PW; i += 256) {
        int h = i / PW, w = i % PW;
        const float* r = xs + h * HWD + w * 4;
        float v = ba + r[0]*wa0 + r[1]*wa1 + r[2]*wa2 + r[3]*wa3;
        y1s[i] = fmaxf(v, 0.f);
    }
    if (tid < PP) {
        int h = tid / PW, w = tid % PW;
        float s = 0.f;
        #pragma unroll
        for (int r = 0; r < 4; ++r) {
            const float* rr = xs + (h*4 + r) * HWD + w * 4;
            s += rr[0] + rr[1] + rr[2] + rr[3];
        }
        pools[tid] = s * (1.f / 16.f);
    }
    __syncthreads();

    if (tid < PP) {
        int h = tid / PW, w = tid % PW;
        float* lp = l_pre + ((size_t)(b * C_DIM + c)) * M_TOT;
        float v1 = b1b[c];
        v1 += y1s[(h*4+0)*PW + w] * w1b[c*4+0];
        v1 += y1s[(h*4+1)*PW + w] * w1b[c*4+1];
        v1 += y1s[(h*4+2)*PW + w] * w1b[c*4+2];
        v1 += y1s[(h*4+3)*PW + w] * w1b[c*4+3];
        lp[tid] = fmaxf(v1, 0.f);
        float v2 = b2[c];
        #pragma unroll
        for (int r = 0; r < 4; ++r)
            #pragma unroll
            for (int s2 = 0; s2 < 4; ++s2)
                v2 += xs[(h*4+r)*HWD + w*4 + s2] * w2[c*16 + r*4 + s2];
        lp[PP + tid] = fmaxf(v2, 0.f);
        float v3 = b3[c];
        #pragma unroll
        for (int dh = -1; dh <= 1; ++dh)
            #pragma unroll
            for (int dw = -1; dw <= 1; ++dw) {
                int hh = h + dh, ww = w + dw;
                if (hh >= 0 && hh < PW && ww >= 0 && ww < PW)
                    v3 += pools[hh*PW + ww] * w3[c*9 + (dh+1)*3 + (dw+1)];
            }
        lp[2*PP + tid] = fmaxf(v3, 0.f);
    }
}

__device__ __forceinline__ void xpose_body(
    int bx, int by, int bz, int tid, float* sbuf,
    const float* __restrict__ x, short* __restrict__ Xb)
{
    float (*sx)[68] = (float(*)[68])sbuf;
    const int n0 = bx * 64, c0 = by * 64, b = bz;
    #pragma unroll
    for (int it = 0; it < 4; ++it) {
        int idx = tid + it * 256;
        int cr = idx >> 4, n4 = (idx & 15) * 4;
        float4 v = *(const float4*)(x + ((size_t)(b * C_DIM + c0 + cr)) * NPIX + n0 + n4);
        *(float4*)&sx[cr][n4] = v;
    }
    __syncthreads();
    #pragma unroll
    for (int p = 0; p < 2; ++p) {
        int idx = tid + p * 256;
        int nr = idx >> 3, cg = (idx & 7) * 8;
        short ov[8];
        #pragma unroll
        for (int e = 0; e < 8; ++e) ov[e] = f2bs(sx[cg + e][nr]);
        *(float4*)&Xb[((size_t)(b * NPIX + n0 + nr)) * C_DIM + c0 + cg] = *(float4*)ov;
    }
}

__device__ __forceinline__ void wconv_body(
    int blk, int tid,
    const float* __restrict__ Wq, const float* __restrict__ Wkv,
    short* __restrict__ Wqb, short* __restrict__ Wkvb)
{
    int i = (blk * 256 + tid) * 4;
    if (i < 262144) {
        float4 v = *(const float4*)(Wq + i);
        short o[4] = {f2bs(v.x), f2bs(v.y), f2bs(v.z), f2bs(v.w)};
        *(short4*)(Wqb + i) = *(short4*)o;
    } else {
        int j = i - 262144;
        float4 v = *(const float4*)(Wkv + j);
        short o[4] = {f2bs(v.x), f2bs(v.y), f2bs(v.z), f2bs(v.w)};
        *(short4*)(Wkvb + j) = *(short4*)o;
    }
}

__global__ __launch_bounds__(256) void k_front(
    const float* __restrict__ x,
    const float* __restrict__ Wq, const float* __restrict__ Wkv,
    short* __restrict__ Wqb, short* __restrict__ Wkvb,
    short* __restrict__ Xb,
    const float* __restrict__ w1a, const float* __restrict__ b1a,
    const float* __restrict__ w1b, const float* __restrict__ b1b,
    const float* __restrict__ w2,  const float* __restrict__ b2,
    const float* __restrict__ w3,  const float* __restrict__ b3,
    float* __restrict__ l_pre)
{
    __shared__ float sbuf[4368];   // max(branches 4116, xpose 4352)
    const int bid = blockIdx.x, tid = threadIdx.x;
    if (bid < 4096) {
        branches_body(bid & 511, bid >> 9, tid, sbuf,
                      x, w1a, b1a, w1b, b1b, w2, b2, w3, b3, l_pre);
    } else if (bid < 7232) {
        int i2 = bid - 4096;               // 3136 = 49*8*8
        xpose_body(i2 % 49, (i2 / 49) & 7, i2 / 392, tid, sbuf, x, Xb);
    } else {
        wconv_body(bid - 7232, tid, Wq, Wkv, Wqb, Wkvb);
    }
}

// ===========================================================================
// K2: fused mid — staged q-GEMM (m97 pattern, async gl_lds16) ∪ stats.
// (exact R5 config)
// ===========================================================================

__device__ __forceinline__ void gemm_q_body(
    int bx, int by, int tid, short* As, short* Bs,
    const short* __restrict__ A, const short* __restrict__ Bw,
    const float* __restrict__ bias, short* __restrict__ Qb)
{
    const int lane = tid & 63, w = tid >> 6;
    const int l15 = lane & 15, quad = lane >> 4;
    const int wr = w & 1, wc = w >> 1;
    const int row0 = bx * 128, col0 = by * 128;
    const int lr8 = lane >> 3, lc8 = (lane & 7) * 8;

    f32x4 acc[4][4] = {};

    for (int c0 = 0; c0 < 512; c0 += 64) {
        __syncthreads();
        #pragma unroll
        for (int it = 0; it < 4; ++it) {
            int r = w * 32 + it * 8;
            gl_lds16(A  + (size_t)(row0 + r + lr8) * 512 + c0 + lc8, &As[r * 64]);
            gl_lds16(Bw + (size_t)(col0 + r + lr8) * 512 + c0 + lc8, &Bs[r * 64]);
        }
        __syncthreads();
        #pragma unroll
        for (int ks = 0; ks < 2; ++ks) {
            bf16x8 af[4], bf[4];
            #pragma unroll
            for (int t = 0; t < 4; ++t) {
                af[t] = *(const bf16x8*)&As[(wr*64 + t*16 + l15)*64 + ks*32 + quad*8];
                bf[t] = *(const bf16x8*)&Bs[(wc*64 + t*16 + l15)*64 + ks*32 + quad*8];
            }
            #pragma unroll
            for (int nt = 0; nt < 4; ++nt)
                #pragma unroll
                for (int mt = 0; mt < 4; ++mt)
                    acc[nt][mt] = __builtin_amdgcn_mfma_f32_16x16x32_bf16(
                        af[nt], bf[mt], acc[nt][mt], 0, 0, 0);
        }
    }

    #pragma unroll
    for (int nt = 0; nt < 4; ++nt) {
        int row_t = row0 + wr * 64 + nt * 16 + quad * 4;
        #pragma unroll
        for (int mt = 0; mt < 4; ++mt) {
            int col = col0 + wc * 64 + mt * 16 + l15;
            float bv = bias[col];
            int h = col >> 6, d = col & 63;
            #pragma unroll
            for (int r = 0; r < 4; ++r) {
                int row_g = row_t + r;
                int b = row_g / N_SEQ;
                int n = row_g - b * N_SEQ;
                Qb[(((size_t)(b * HEADS + h)) * N_SEQ + n) * HD + d] =
                    f2bs((acc[nt][mt][r] + bv) * SM_SCALE_LOG2E);
            }
        }
    }
}

__device__ __forceinline__ void stats_body(
    int sx_, int sb_, int tid, float* red,
    const float* __restrict__ l_pre, float2* __restrict__ stats)
{
    float* ssum = red;
    float* ssq  = red + 256;
    const int ml = tid & 63, cg = tid >> 6;
    const int b = sb_;
    const int m = sx_ * 64 + ml;
    float s = 0.f, q = 0.f;
    if (m < M_TOT) {
        const float* base = l_pre + ((size_t)b * C_DIM + cg * 128) * M_TOT + m;
        for (int c = 0; c < 128; ++c) {
            float v = base[(size_t)c * M_TOT];
            s += v; q += v * v;
        }
    }
    ssum[cg*64 + ml] = s; ssq[cg*64 + ml] = q;
    __syncthreads();
    if (tid < 64 && sx_ * 64 + tid < M_TOT) {
        float ts = ssum[tid] + ssum[64+tid] + ssum[128+tid] + ssum[192+tid];
        float tq = ssq[tid] + ssq[64+tid] + ssq[128+tid] + ssq[192+tid];
        float mu = ts * (1.f / 512.f);
        float var = tq * (1.f / 512.f) - mu * mu;
        stats[(size_t)b * M_TOT + sx_ * 64 + tid] =
            make_float2(mu, rsqrtf(var + 1e-5f));
    }
}

__global__ __launch_bounds__(256) void k_mid(
    const short* __restrict__ Xb, const short* __restrict__ Wqb,
    const float* __restrict__ bq, short* __restrict__ Qb,
    const float* __restrict__ l_pre, float2* __restrict__ stats)
{
    __shared__ short sb2[16384];   // gemm: As|Bs (32 KB); stats: 2 KB reduce
    const int bid = blockIdx.x, tid = threadIdx.x;
    if (bid < 784) {
        gemm_q_body(bid % 196, bid / 196, tid, sb2, sb2 + 8192,
                    Xb, Wqb, bq, Qb);
    } else {
        int sid = bid - 784;       // 80 = 10*8
        stats_body(sid % 10, sid / 10, tid, (float*)sb2, l_pre, stats);
    }
}

// ---------------------------------------------------------------------------
// Kernel L: LN(l_pre) transposed -> Lb [BM_PAD, C] bf16.
// ---------------------------------------------------------------------------
__global__ __launch_bounds__(256) void k_lnt(
    const float* __restrict__ l_pre, const float2* __restrict__ stats,
    const float* __restrict__ gamma, const float* __restrict__ beta,
    short* __restrict__ Lb)
{
    __shared__ float sx[64][68];
    const int tid = threadIdx.x;
    const int m0 = blockIdx.x * 64, c0 = blockIdx.y * 64, b = blockIdx.z;
    #pragma unroll
    for (int it = 0; it < 4; ++it) {
        int idx = tid + it * 256;
        int cr = idx >> 4, m4 = (idx & 15) * 4;
        float4 v = {0.f, 0.f, 0.f, 0.f};
        if (m0 + m4 < M_TOT)
            v = *(const float4*)(l_pre + ((size_t)(b * C_DIM + c0 + cr)) * M_TOT + m0 + m4);
        *(float4*)&sx[cr][m4] = v;
    }
    __syncthreads();
    #pragma unroll
    for (int p = 0; p < 2; ++p) {
        int idx = tid + p * 256;
        int mr = idx >> 3, cg = (idx & 7) * 8;
        int m = m0 + mr;
        float mu = 0.f, rstd = 0.f;
        if (m < M_TOT) {
            float2 st = stats[(size_t)b * M_TOT + m];
            mu = st.x; rstd = st.y;
        }
        short ov[8];
        #pragma unroll
        for (int e = 0; e < 8; ++e) {
            int c = c0 + cg + e;
            ov[e] = f2bs((sx[cg + e][mr] - mu) * rstd * gamma[c] + beta[c]);
        }
        if (m < M_TOT)
            *(float4*)&Lb[((size_t)(b * M_TOT + m)) * C_DIM + c0 + cg] = *(float4*)ov;
    }
}

// ---------------------------------------------------------------------------
// K4: kv GEMM (staged m97 pattern, exact R5 config).
// ---------------------------------------------------------------------------
__global__ __launch_bounds__(256) void k_gemm_kv(
    const short* __restrict__ A, const short* __restrict__ Bw,
    const float* __restrict__ bias,
    short* __restrict__ Kb, short* __restrict__ Vt)
{
    __shared__ short As[128 * 64];
    __shared__ short Bs[128 * 64];
    const int tid = threadIdx.x;
    const int lane = tid & 63, w = tid >> 6;
    const int l15 = lane & 15, quad = lane >> 4;
    const int wr = w & 1, wc = w >> 1;
    const int row0 = blockIdx.x * 128, col0 = blockIdx.y * 128;
    const int lr8 = lane >> 3, lc8 = (lane & 7) * 8;

    f32x4 acc[4][4] = {};

    for (int c0 = 0; c0 < 512; c0 += 64) {
        __syncthreads();
        #pragma unroll
        for (int it = 0; it < 4; ++it) {
            int r = w * 32 + it * 8;
            gl_lds16(A  + (size_t)(row0 + r + lr8) * 512 + c0 + lc8, &As[r * 64]);
            gl_lds16(Bw + (size_t)(col0 + r + lr8) * 512 + c0 + lc8, &Bs[r * 64]);
        }
        __syncthreads();
        #pragma unroll
        for (int ks = 0; ks < 2; ++ks) {
            bf16x8 af[4], bf[4];
            #pragma unroll
            for (int t = 0; t < 4; ++t) {
                af[t] = *(const bf16x8*)&As[(wr*64 + t*16 + l15)*64 + ks*32 + quad*8];
                bf[t] = *(const bf16x8*)&Bs[(wc*64 + t*16 + l15)*64 + ks*32 + quad*8];
            }
            #pragma unroll
            for (int nt = 0; nt < 4; ++nt)
                #pragma unroll
                for (int mt = 0; mt < 4; ++mt)
                    acc[nt][mt] = __builtin_amdgcn_mfma_f32_16x16x32_bf16(
                        af[nt], bf[mt], acc[nt][mt], 0, 0, 0);
        }
    }

    #pragma unroll
    for (int nt = 0; nt < 4; ++nt) {
        int row_t = row0 + wr * 64 + nt * 16 + quad * 4;
        #pragma unroll
        for (int mt = 0; mt < 4; ++mt) {
            int col = col0 + wc * 64 + mt * 16 + l15;
            float bv = bias[col];
            #pragma unroll
            for (int r = 0; r < 4; ++r) {
                int row_g = row_t + r;
                float v = acc[nt][mt][r] + bv;
                if (row_g < BM_ROWS) {
                    int b = row_g / M_TOT;
                    int m = row_g - b * M_TOT;
                    if (col < 512) {
                        int h = col >> 6, d = col & 63;
                        Kb[(((size_t)(b * HEADS + h)) * M_TOT + m) * HD + d] = f2bs(v);
                    } else {
                        int jj = col - 512, h = jj >> 6, d = jj & 63;
                        Vt[(((size_t)(b * HEADS + h)) * HD + d) * M_TOT + m] = f2bs(v);
                    }
                }
            }
        }
    }
}

// ---------------------------------------------------------------------------
// Kernel E: phase-staged persistent-KV attention, SINGLE-strip waves.
// Grid = (14 n-splits, h, b) = 896 blocks, 1024 threads (16 waves).
// LDS 80.8 KB (K[304][68] + V^T[64][308]); body sized for <=64 total regs so
// the HW can co-schedule 2 blocks/CU (no forced waves-per-eu — R9/R10's
// forced cap caused catastrophic scratch spills at VGPR=32).
// Waves 0..13 each own ONE 16-row Q strip (14x16 = 224 rows/block, exact);
// waves 14..15 stage-only. Phase 1: j 0..303 (19 steps). Phase 2: j 304..587
// + 4 zeroed pads (18 steps, pad P masked at quad==3 of the last step).
// ---------------------------------------------------------------------------
__global__ __launch_bounds__(1024) void k_attn(
    const short* __restrict__ Qb, const short* __restrict__ Kb,
    const short* __restrict__ Vt, float* __restrict__ out)
{
    extern __shared__ short smem[];
    short* Ks = smem;                        // [304][68]
    short* Vs = smem + KROWS_P1 * KS_STRIDE; // [64][308]

    const int tid = threadIdx.x;
    const int lane = tid & 63, w = tid >> 6;
    const int l15 = lane & 15, quad = lane >> 4;
    const int q14 = blockIdx.x, h = blockIdx.y, b = blockIdx.z;
    const size_t bh = (size_t)(b * HEADS + h);
    const size_t kbase = bh * M_TOT * HD;          // Kb [B,h,M,d]
    const size_t vbase = bh * (size_t)HD * M_TOT;  // Vt [B,h,d,M]

    const bool cw = (w < 14);                // compute wave
    const int n = q14 * QROWS_PER_BLK + w * 16 + l15;   // this wave's Q row

    bf16x8 qf0, qf1;
    if (cw) {
        const short* qp = Qb + (bh * N_SEQ + n) * HD + quad * 8;
        qf0 = *(const bf16x8*)qp;
        qf1 = *(const bf16x8*)(qp + 32);
    }

    f32x4 oacc[4] = {};
    f32x4 rsacc = {};
    const bf16x4 ones = {(short)0x3F80, (short)0x3F80, (short)0x3F80, (short)0x3F80};
    const float tmask = (quad == 3) ? 0.f : 1.f;

    auto STAGE = [&](int jb, int rows, bool pad) {
        // K: rows x 64d, float4-coalesced
        for (int i = tid; i < rows * 8; i += 1024) {
            int row = i >> 3, seg = i & 7;
            *(float4*)&Ks[row * KS_STRIDE + seg * 8] =
                *(const float4*)(Kb + kbase + (size_t)(jb + row) * 64 + seg * 8);
        }
        // V^T: 64 d-rows x rows j-cols, float2-coalesced (16 thr/row)
        {
            int row = tid >> 4, tg = tid & 15;
            const short* src = Vt + vbase + (size_t)row * M_TOT + jb;
            for (int jj = tg; jj < rows / 4; jj += 16)
                *(float2*)&Vs[row * VS_STRIDE + jj * 4] = *(const float2*)(src + jj * 4);
        }
        if (pad) {
            if (tid < 256) {                 // K pad rows 284..287
                int r = tid >> 6, cc = tid & 63;
                Ks[(284 + r) * KS_STRIDE + cc] = 0;
            } else if (tid < 512) {          // V pad cols 284..287
                int idx = tid - 256;
                int row = idx >> 2, cc = idx & 3;
                Vs[row * VS_STRIDE + 284 + cc] = 0;
            }
        }
    };

    auto STEP = [&](int j0, bool tail) {
        const short* kr = &Ks[(j0 + l15) * KS_STRIDE + quad * 8];
        bf16x8 kf0 = *(const bf16x8*)kr;
        bf16x8 kf1 = *(const bf16x8*)(kr + 32);
        const short* vr = &Vs[l15 * VS_STRIDE + j0 + quad * 4];
        bf16x4 v0 = *(const bf16x4*)vr;
        bf16x4 v1 = *(const bf16x4*)(vr + 16 * VS_STRIDE);
        bf16x4 v2 = *(const bf16x4*)(vr + 32 * VS_STRIDE);
        bf16x4 v3 = *(const bf16x4*)(vr + 48 * VS_STRIDE);

        f32x4 s = {};
        s = __builtin_amdgcn_mfma_f32_16x16x32_bf16(kf0, qf0, s, 0, 0, 0);
        s = __builtin_amdgcn_mfma_f32_16x16x32_bf16(kf1, qf1, s, 0, 0, 0);

        float p[4];
        #pragma unroll
        for (int r = 0; r < 4; ++r) p[r] = fexp2(s[r]);
        if (tail) {
            #pragma unroll
            for (int r = 0; r < 4; ++r) p[r] *= tmask;
        }
        unsigned ua[2] = {pkbf(p[0], p[1]), pkbf(p[2], p[3])};
        bf16x4 pb;
        __builtin_memcpy(&pb, ua, 8);

        rsacc = mfma16(ones, pb, rsacc);
        oacc[0] = mfma16(v0, pb, oacc[0]);
        oacc[1] = mfma16(v1, pb, oacc[1]);
        oacc[2] = mfma16(v2, pb, oacc[2]);
        oacc[3] = mfma16(v3, pb, oacc[3]);
    };

    // ---- phase 1: j in [0, 304)
    STAGE(0, 304, false);
    __syncthreads();
    if (cw) {
        #pragma unroll 1
        for (int j0 = 0; j0 < 304; j0 += 16) STEP(j0, false);
    }
    __syncthreads();   // all waves: computes done before re-stage

    // ---- phase 2: j in [304, 588) + 4 pad rows
    STAGE(304, 284, true);
    __syncthreads();
    if (cw) {
        #pragma unroll 1
        for (int j0 = 0; j0 < 272; j0 += 16) STEP(j0, false);
        STEP(272, true);   // pad rows 284..287 masked via quad==3

        const float inv = 1.f / rsacc[0];
        float* orow = out + ((size_t)b * N_SEQ + n) * C_DIM + h * HD;
        #pragma unroll
        for (int dt = 0; dt < 4; ++dt) {
            float4 o;
            o.x = oacc[dt][0] * inv; o.y = oacc[dt][1] * inv;
            o.z = oacc[dt][2] * inv; o.w = oacc[dt][3] * inv;
            *(float4*)&orow[dt * 16 + quad * 4] = o;
        }
    }
}

// ---------------------------------------------------------------------------
// Workspace layout (R5-measured):
//   Xb    : ws + 0          (25,690,112)  — written K1, read K2
//   Wqb   : ws + 25,690,112 (   524,288)  — written K1, read K2
//   Wkvb  : ws + 26,214,400 ( 1,048,576)  — written K1, read K4
//   l_pre : ws + 27,262,976 ( 9,633,792)  — written K1, read K2/K3;
//   Kb/Vt :   same region                — written K4 (l_pre dead), read K5
//   Qb    : ws + 36,896,768 (25,690,112)  — written K2, read K5
// stats/Lb live in d_out (first 4.9 MB); consumed by K3/K4, then K5 (attn)
// overwrites every element of out.
// ---------------------------------------------------------------------------
extern "C" void kernel_launch(void* const* d_in, const int* in_sizes, int n_in,
                              void* d_out, int out_size, void* d_ws, size_t ws_size,
                              hipStream_t stream) {
    const float* x     = (const float*)d_in[0];
    const float* Wq    = (const float*)d_in[1];
    const float* bq    = (const float*)d_in[2];
    const float* Wkv   = (const float*)d_in[3];
    const float* bkv   = (const float*)d_in[4];
    const float* w1a   = (const float*)d_in[5];
    const float* b1a   = (const float*)d_in[6];
    const float* w1b   = (const float*)d_in[7];
    const float* b1b   = (const float*)d_in[8];
    const float* w2    = (const float*)d_in[9];
    const float* b2    = (const float*)d_in[10];
    const float* w3    = (const float*)d_in[11];
    const float* b3    = (const float*)d_in[12];
    const float* gamma = (const float*)d_in[13];
    const float* beta  = (const float*)d_in[14];
    float* out = (float*)d_out;

    char* ws = (char*)d_ws;
    short*  Xb    = (short*)ws;
    short*  Wqb   = (short*)(ws + 25690112);
    short*  Wkvb  = (short*)(ws + 26214400);
    float*  l_pre = (float*)(ws + 27262976);       // shares region with Kb/Vt
    short*  Kb    = (short*)(ws + 27262976);       // written after l_pre dead
    short*  Vt    = (short*)(ws + 32079872);
    short*  Qb    = (short*)(ws + 36896768);
    float2* stats = (float2*)d_out;                // 37,632 B in out-buffer
    short*  Lb    = (short*)((char*)d_out + 65536); // 4,849,664 B in out-buffer

    hipFuncSetAttribute((const void*)k_attn,
                        hipFuncAttributeMaxDynamicSharedMemorySize,
                        ATTN_LDS_BYTES);

    k_front<<<8000, 256, 0, stream>>>(
        x, Wq, Wkv, Wqb, Wkvb, Xb,
        w1a, b1a, w1b, b1b, w2, b2, w3, b3, l_pre);
    k_mid<<<864, 256, 0, stream>>>(Xb, Wqb, bq, Qb, l_pre, stats);
    k_lnt<<<dim3(10, 8, BATCH), 256, 0, stream>>>(l_pre, stats, gamma, beta, Lb);
    k_gemm_kv<<<dim3(37, 8), 256, 0, stream>>>(Lb, Wkvb, bkv, Kb, Vt);
    k_attn<<<dim3(NSPLIT, HEADS, BATCH), 1024, ATTN_LDS_BYTES, stream>>>(Qb, Kb, Vt, out);
}

// Round 12
// 258.045 us; speedup vs baseline: 1.5021x; 1.2869x over previous
//
#include <hip/hip_runtime.h>
#include <hip/hip_bf16.h>

#define BATCH   8
#define C_DIM   512
#define HWD     56
#define NPIX    3136   // 56*56
#define PW      14
#define PP      196    // 14*14
#define M_TOT   588    // 3*196
#define BM_ROWS 4704   // 8*588
#define BM_PAD  4736   // padded to 37*128
#define HEADS   8
#define HD      64
#define N_SEQ   3136
#define SM_SCALE 0.125f
// SM_SCALE * log2(e): folded into Q at the q-GEMM epilogue, so the attention
// inner loop computes p = exp2(s) with NO multiply at all.
#define SM_SCALE_LOG2E 0.1803368801111204f

// attention LDS geometry (R5-measured best: whole-head K+V resident, 1 blk/CU)
#define KS_STRIDE 68            // shorts per K row (34 words: frag reads <=2-way)
#define KS_ROWS   592           // 588 + 4 zero pad rows
#define VS_STRIDE 596           // shorts per V^T row (298 words: <=2-way)
#define ATTN_LDS_SHORTS (KS_ROWS * KS_STRIDE + 64 * VS_STRIDE)   // 78400
#define ATTN_LDS_BYTES  (ATTN_LDS_SHORTS * 2)                    // 156800

typedef __attribute__((ext_vector_type(8))) short bf16x8;
typedef __attribute__((ext_vector_type(4))) short bf16x4;
typedef __attribute__((ext_vector_type(4))) float f32x4;

__device__ __forceinline__ short f2bs(float f) {
    __hip_bfloat16 h = __float2bfloat16(f);
    return *reinterpret_cast<short*>(&h);
}
__device__ __forceinline__ unsigned pkbf(float lo, float hi) {
    __hip_bfloat162 t = __float22bfloat162_rn(make_float2(lo, hi));
    return *reinterpret_cast<unsigned*>(&t);
}
__device__ __forceinline__ float fexp2(float x) {
#if __has_builtin(__builtin_amdgcn_exp2f)
    return __builtin_amdgcn_exp2f(x);
#else
    return exp2f(x);
#endif
}

// 16x16x16 bf16 MFMA (K=16): B-operand layout k=quad*4+jj, n=l15 — matches
// the C/D layout of our S^T tiles directly (no transpose needed for PV).
__device__ __forceinline__ f32x4 mfma16(bf16x4 a, bf16x4 b, f32x4 c) {
#if __has_builtin(__builtin_amdgcn_mfma_f32_16x16x16bf16_1k)
    return __builtin_amdgcn_mfma_f32_16x16x16bf16_1k(a, b, c, 0, 0, 0);
#elif __has_builtin(__builtin_amdgcn_mfma_f32_16x16x16_bf16)
    return __builtin_amdgcn_mfma_f32_16x16x16_bf16(a, b, c, 0, 0, 0);
#else
    asm volatile("v_mfma_f32_16x16x16_bf16 %0, %1, %2, %0\n\ts_nop 7\n\ts_nop 1"
                 : "+v"(c) : "v"(a), "v"(b));
    return c;
#endif
}

// async 16B global->LDS copy (m97 pattern, wave-uniform LDS base).
__device__ __forceinline__ void gl_lds16(const void* g, void* l) {
    __builtin_amdgcn_global_load_lds(
        (const __attribute__((address_space(1))) void*)g,
        (__attribute__((address_space(3))) void*)l, 16, 0, 0);
}

// ===========================================================================
// K1: fused front-end — branches (4096) ∪ xpose (3136) ∪ wconv (768).
// ===========================================================================

__device__ __forceinline__ void branches_body(
    int c, int b, int tid, float* sbuf,
    const float* __restrict__ x,
    const float* __restrict__ w1a, const float* __restrict__ b1a,
    const float* __restrict__ w1b, const float* __restrict__ b1b,
    const float* __restrict__ w2,  const float* __restrict__ b2,
    const float* __restrict__ w3,  const float* __restrict__ b3,
    float* __restrict__ l_pre)
{
    float* xs    = sbuf;            // 3136
    float* y1s   = sbuf + 3136;     // 784
    float* pools = sbuf + 3920;     // 196
    const float* xp = x + ((size_t)(b * C_DIM + c)) * NPIX;
    for (int i = tid; i < NPIX / 4; i += 256)
        ((float4*)xs)[i] = ((const float4*)xp)[i];
    __syncthreads();

    const float wa0 = w1a[c*4+0], wa1 = w1a[c*4+1], wa2 = w1a[c*4+2], wa3 = w1a[c*4+3];
    const float ba = b1a[c];
    for (int i = tid; i < HWD * PW; i += 256) {
        int h = i / PW, w = i % PW;
        const float* r = xs + h * HWD + w * 4;
        float v = ba + r[0]*wa0 + r[1]*wa1 + r[2]*wa2 + r[3]*wa3;
        y1s[i] = fmaxf(v, 0.f);
    }
    if (tid < PP) {
        int h = tid / PW, w = tid % PW;
        float s = 0.f;
        #pragma unroll
        for (int r = 0; r < 4; ++r) {
            const float* rr = xs + (h*4 + r) * HWD + w * 4;
            s += rr[0] + rr[1] + rr[2] + rr[3];
        }
        pools[tid] = s * (1.f / 16.f);
    }
    __syncthreads();

    if (tid < PP) {
        int h = tid / PW, w = tid % PW;
        float* lp = l_pre + ((size_t)(b * C_DIM + c)) * M_TOT;
        float v1 = b1b[c];
        v1 += y1s[(h*4+0)*PW + w] * w1b[c*4+0];
        v1 += y1s[(h*4+1)*PW + w] * w1b[c*4+1];
        v1 += y1s[(h*4+2)*PW + w] * w1b[c*4+2];
        v1 += y1s[(h*4+3)*PW + w] * w1b[c*4+3];
        lp[tid] = fmaxf(v1, 0.f);
        float v2 = b2[c];
        #pragma unroll
        for (int r = 0; r < 4; ++r)
            #pragma unroll
            for (int s2 = 0; s2 < 4; ++s2)
                v2 += xs[(h*4+r)*HWD + w*4 + s2] * w2[c*16 + r*4 + s2];
        lp[PP + tid] = fmaxf(v2, 0.f);
        float v3 = b3[c];
        #pragma unroll
        for (int dh = -1; dh <= 1; ++dh)
            #pragma unroll
            for (int dw = -1; dw <= 1; ++dw) {
                int hh = h + dh, ww = w + dw;
                if (hh >= 0 && hh < PW && ww >= 0 && ww < PW)
                    v3 += pools[hh*PW + ww] * w3[c*9 + (dh+1)*3 + (dw+1)];
            }
        lp[2*PP + tid] = fmaxf(v3, 0.f);
    }
}

__device__ __forceinline__ void xpose_body(
    int bx, int by, int bz, int tid, float* sbuf,
    const float* __restrict__ x, short* __restrict__ Xb)
{
    float (*sx)[68] = (float(*)[68])sbuf;
    const int n0 = bx * 64, c0 = by * 64, b = bz;
    #pragma unroll
    for (int it = 0; it < 4; ++it) {
        int idx = tid + it * 256;
        int cr = idx >> 4, n4 = (idx & 15) * 4;
        float4 v = *(const float4*)(x + ((size_t)(b * C_DIM + c0 + cr)) * NPIX + n0 + n4);
        *(float4*)&sx[cr][n4] = v;
    }
    __syncthreads();
    #pragma unroll
    for (int p = 0; p < 2; ++p) {
        int idx = tid + p * 256;
        int nr = idx >> 3, cg = (idx & 7) * 8;
        short ov[8];
        #pragma unroll
        for (int e = 0; e < 8; ++e) ov[e] = f2bs(sx[cg + e][nr]);
        *(float4*)&Xb[((size_t)(b * NPIX + n0 + nr)) * C_DIM + c0 + cg] = *(float4*)ov;
    }
}

__device__ __forceinline__ void wconv_body(
    int blk, int tid,
    const float* __restrict__ Wq, const float* __restrict__ Wkv,
    short* __restrict__ Wqb, short* __restrict__ Wkvb)
{
    int i = (blk * 256 + tid) * 4;
    if (i < 262144) {
        float4 v = *(const float4*)(Wq + i);
        short o[4] = {f2bs(v.x), f2bs(v.y), f2bs(v.z), f2bs(v.w)};
        *(short4*)(Wqb + i) = *(short4*)o;
    } else {
        int j = i - 262144;
        float4 v = *(const float4*)(Wkv + j);
        short o[4] = {f2bs(v.x), f2bs(v.y), f2bs(v.z), f2bs(v.w)};
        *(short4*)(Wkvb + j) = *(short4*)o;
    }
}

__global__ __launch_bounds__(256) void k_front(
    const float* __restrict__ x,
    const float* __restrict__ Wq, const float* __restrict__ Wkv,
    short* __restrict__ Wqb, short* __restrict__ Wkvb,
    short* __restrict__ Xb,
    const float* __restrict__ w1a, const float* __restrict__ b1a,
    const float* __restrict__ w1b, const float* __restrict__ b1b,
    const float* __restrict__ w2,  const float* __restrict__ b2,
    const float* __restrict__ w3,  const float* __restrict__ b3,
    float* __restrict__ l_pre)
{
    __shared__ float sbuf[4368];   // max(branches 4116, xpose 4352)
    const int bid = blockIdx.x, tid = threadIdx.x;
    if (bid < 4096) {
        branches_body(bid & 511, bid >> 9, tid, sbuf,
                      x, w1a, b1a, w1b, b1b, w2, b2, w3, b3, l_pre);
    } else if (bid < 7232) {
        int i2 = bid - 4096;               // 3136 = 49*8*8
        xpose_body(i2 % 49, (i2 / 49) & 7, i2 / 392, tid, sbuf, x, Xb);
    } else {
        wconv_body(bid - 7232, tid, Wq, Wkv, Wqb, Wkvb);
    }
}

// ===========================================================================
// K2: fused mid — gemm_q (784 blocks) ∪ stats (80 blocks).
// ===========================================================================

__device__ __forceinline__ void gemm_q_body(
    int bx, int by, int tid, short* As, short* Bs,
    const short* __restrict__ A, const short* __restrict__ Bw,
    const float* __restrict__ bias, short* __restrict__ Qb)
{
    const int lane = tid & 63, w = tid >> 6;
    const int l15 = lane & 15, quad = lane >> 4;
    const int wr = w & 1, wc = w >> 1;
    const int row0 = bx * 128, col0 = by * 128;
    const int lr8 = lane >> 3, lc8 = (lane & 7) * 8;

    f32x4 acc[4][4] = {};

    for (int c0 = 0; c0 < 512; c0 += 64) {
        __syncthreads();
        #pragma unroll
        for (int it = 0; it < 4; ++it) {
            int r = w * 32 + it * 8;
            gl_lds16(A  + (size_t)(row0 + r + lr8) * 512 + c0 + lc8, &As[r * 64]);
            gl_lds16(Bw + (size_t)(col0 + r + lr8) * 512 + c0 + lc8, &Bs[r * 64]);
        }
        __syncthreads();
        #pragma unroll
        for (int ks = 0; ks < 2; ++ks) {
            bf16x8 af[4], bf[4];
            #pragma unroll
            for (int t = 0; t < 4; ++t) {
                af[t] = *(const bf16x8*)&As[(wr*64 + t*16 + l15)*64 + ks*32 + quad*8];
                bf[t] = *(const bf16x8*)&Bs[(wc*64 + t*16 + l15)*64 + ks*32 + quad*8];
            }
            #pragma unroll
            for (int nt = 0; nt < 4; ++nt)
                #pragma unroll
                for (int mt = 0; mt < 4; ++mt)
                    acc[nt][mt] = __builtin_amdgcn_mfma_f32_16x16x32_bf16(
                        af[nt], bf[mt], acc[nt][mt], 0, 0, 0);
        }
    }

    #pragma unroll
    for (int nt = 0; nt < 4; ++nt) {
        int row_t = row0 + wr * 64 + nt * 16 + quad * 4;
        #pragma unroll
        for (int mt = 0; mt < 4; ++mt) {
            int col = col0 + wc * 64 + mt * 16 + l15;
            float bv = bias[col];
            int h = col >> 6, d = col & 63;
            #pragma unroll
            for (int r = 0; r < 4; ++r) {
                int row_g = row_t + r;
                int b = row_g / N_SEQ;
                int n = row_g - b * N_SEQ;
                Qb[(((size_t)(b * HEADS + h)) * N_SEQ + n) * HD + d] =
                    f2bs((acc[nt][mt][r] + bv) * SM_SCALE_LOG2E);
            }
        }
    }
}

__device__ __forceinline__ void stats_body(
    int sx_, int sb_, int tid, float* red,
    const float* __restrict__ l_pre, float2* __restrict__ stats)
{
    float* ssum = red;
    float* ssq  = red + 256;
    const int ml = tid & 63, cg = tid >> 6;
    const int b = sb_;
    const int m = sx_ * 64 + ml;
    float s = 0.f, q = 0.f;
    if (m < M_TOT) {
        const float* base = l_pre + ((size_t)b * C_DIM + cg * 128) * M_TOT + m;
        for (int c = 0; c < 128; ++c) {
            float v = base[(size_t)c * M_TOT];
            s += v; q += v * v;
        }
    }
    ssum[cg*64 + ml] = s; ssq[cg*64 + ml] = q;
    __syncthreads();
    if (tid < 64 && sx_ * 64 + tid < M_TOT) {
        float ts = ssum[tid] + ssum[64+tid] + ssum[128+tid] + ssum[192+tid];
        float tq = ssq[tid] + ssq[64+tid] + ssq[128+tid] + ssq[192+tid];
        float mu = ts * (1.f / 512.f);
        float var = tq * (1.f / 512.f) - mu * mu;
        stats[(size_t)b * M_TOT + sx_ * 64 + tid] =
            make_float2(mu, rsqrtf(var + 1e-5f));
    }
}

__global__ __launch_bounds__(256) void k_mid(
    const short* __restrict__ Xb, const short* __restrict__ Wqb,
    const float* __restrict__ bq, short* __restrict__ Qb,
    const float* __restrict__ l_pre, float2* __restrict__ stats)
{
    __shared__ short sb2[16384];   // gemm: As|Bs (32 KB); stats: 2 KB reduce
    const int bid = blockIdx.x, tid = threadIdx.x;
    if (bid < 784) {
        gemm_q_body(bid % 196, bid / 196, tid, sb2, sb2 + 8192,
                    Xb, Wqb, bq, Qb);
    } else {
        int sid = bid - 784;       // 80 = 10*8
        stats_body(sid % 10, sid / 10, tid, (float*)sb2, l_pre, stats);
    }
}

// ---------------------------------------------------------------------------
// Kernel L: LN(l_pre) transposed -> Lb [BM_PAD, C] bf16.
// ---------------------------------------------------------------------------
__global__ __launch_bounds__(256) void k_lnt(
    const float* __restrict__ l_pre, const float2* __restrict__ stats,
    const float* __restrict__ gamma, const float* __restrict__ beta,
    short* __restrict__ Lb)
{
    __shared__ float sx[64][68];
    const int tid = threadIdx.x;
    const int m0 = blockIdx.x * 64, c0 = blockIdx.y * 64, b = blockIdx.z;
    #pragma unroll
    for (int it = 0; it < 4; ++it) {
        int idx = tid + it * 256;
        int cr = idx >> 4, m4 = (idx & 15) * 4;
        float4 v = {0.f, 0.f, 0.f, 0.f};
        if (m0 + m4 < M_TOT)
            v = *(const float4*)(l_pre + ((size_t)(b * C_DIM + c0 + cr)) * M_TOT + m0 + m4);
        *(float4*)&sx[cr][m4] = v;
    }
    __syncthreads();
    #pragma unroll
    for (int p = 0; p < 2; ++p) {
        int idx = tid + p * 256;
        int mr = idx >> 3, cg = (idx & 7) * 8;
        int m = m0 + mr;
        float mu = 0.f, rstd = 0.f;
        if (m < M_TOT) {
            float2 st = stats[(size_t)b * M_TOT + m];
            mu = st.x; rstd = st.y;
        }
        short ov[8];
        #pragma unroll
        for (int e = 0; e < 8; ++e) {
            int c = c0 + cg + e;
            ov[e] = f2bs((sx[cg + e][mr] - mu) * rstd * gamma[c] + beta[c]);
        }
        if (m < M_TOT)
            *(float4*)&Lb[((size_t)(b * M_TOT + m)) * C_DIM + c0 + cg] = *(float4*)ov;
    }
}

// ---------------------------------------------------------------------------
// K4: kv GEMM (staged m97 pattern).
// ---------------------------------------------------------------------------
__global__ __launch_bounds__(256) void k_gemm_kv(
    const short* __restrict__ A, const short* __restrict__ Bw,
    const float* __restrict__ bias,
    short* __restrict__ Kb, short* __restrict__ Vt)
{
    __shared__ short As[128 * 64];
    __shared__ short Bs[128 * 64];
    const int tid = threadIdx.x;
    const int lane = tid & 63, w = tid >> 6;
    const int l15 = lane & 15, quad = lane >> 4;
    const int wr = w & 1, wc = w >> 1;
    const int row0 = blockIdx.x * 128, col0 = blockIdx.y * 128;
    const int lr8 = lane >> 3, lc8 = (lane & 7) * 8;

    f32x4 acc[4][4] = {};

    for (int c0 = 0; c0 < 512; c0 += 64) {
        __syncthreads();
        #pragma unroll
        for (int it = 0; it < 4; ++it) {
            int r = w * 32 + it * 8;
            gl_lds16(A  + (size_t)(row0 + r + lr8) * 512 + c0 + lc8, &As[r * 64]);
            gl_lds16(Bw + (size_t)(col0 + r + lr8) * 512 + c0 + lc8, &Bs[r * 64]);
        }
        __syncthreads();
        #pragma unroll
        for (int ks = 0; ks < 2; ++ks) {
            bf16x8 af[4], bf[4];
            #pragma unroll
            for (int t = 0; t < 4; ++t) {
                af[t] = *(const bf16x8*)&As[(wr*64 + t*16 + l15)*64 + ks*32 + quad*8];
                bf[t] = *(const bf16x8*)&Bs[(wc*64 + t*16 + l15)*64 + ks*32 + quad*8];
            }
            #pragma unroll
            for (int nt = 0; nt < 4; ++nt)
                #pragma unroll
                for (int mt = 0; mt < 4; ++mt)
                    acc[nt][mt] = __builtin_amdgcn_mfma_f32_16x16x32_bf16(
                        af[nt], bf[mt], acc[nt][mt], 0, 0, 0);
        }
    }

    #pragma unroll
    for (int nt = 0; nt < 4; ++nt) {
        int row_t = row0 + wr * 64 + nt * 16 + quad * 4;
        #pragma unroll
        for (int mt = 0; mt < 4; ++mt) {
            int col = col0 + wc * 64 + mt * 16 + l15;
            float bv = bias[col];
            #pragma unroll
            for (int r = 0; r < 4; ++r) {
                int row_g = row_t + r;
                float v = acc[nt][mt][r] + bv;
                if (row_g < BM_ROWS) {
                    int b = row_g / M_TOT;
                    int m = row_g - b * M_TOT;
                    if (col < 512) {
                        int h = col >> 6, d = col & 63;
                        Kb[(((size_t)(b * HEADS + h)) * M_TOT + m) * HD + d] = f2bs(v);
                    } else {
                        int jj = col - 512, h = jj >> 6, d = jj & 63;
                        Vt[(((size_t)(b * HEADS + h)) * HD + d) * M_TOT + m] = f2bs(v);
                    }
                }
            }
        }
    }
}

// ---------------------------------------------------------------------------
// Kernel E: persistent-KV MFMA attention (best-measured config, 256.6 µs
// total / ~77 µs attn). Grid (4, h, b) = 256 blocks, 16 waves, 156.8 KB LDS,
// 1 block/CU. Structural notes from the session:
//  * R2-R4: register ping-pong prefetch — compiler sinks it (VGPR stays 56);
//    sched_barrier pins kept for the measured-best artifact.
//  * R9-R11: all 2-blocks/CU variants lose — double-strip needs ~90 VGPR
//    (>64 cap for 8 waves/SIMD) and single-strip halves MFMA-per-LDS-read
//    (LDS pipe saturates). This corner of the tradeoff space is optimal.
// ---------------------------------------------------------------------------
__global__ __launch_bounds__(1024) void k_attn(
    const short* __restrict__ Qb, const short* __restrict__ Kb,
    const short* __restrict__ Vt, float* __restrict__ out)
{
    extern __shared__ short smem[];
    short* Ks = smem;                       // [592][68]
    short* Vs = smem + KS_ROWS * KS_STRIDE; // [64][596]

    const int tid = threadIdx.x;
    const int lane = tid & 63, w = tid >> 6;
    const int l15 = lane & 15, quad = lane >> 4;
    const int q4 = blockIdx.x, h = blockIdx.y, b = blockIdx.z;
    const size_t bh = (size_t)(b * HEADS + h);
    const size_t kbase = bh * M_TOT * HD;          // Kb [B,h,M,d]
    const size_t vbase = bh * (size_t)HD * M_TOT;  // Vt [B,h,d,M]

    // ---- stage K: 588 rows x 64 d (4704 float4 over 1024 threads)
    for (int i = tid; i < 4704; i += 1024) {
        int row = i >> 3, seg = i & 7;
        *(float4*)&Ks[row * KS_STRIDE + seg * 8] =
            *(const float4*)(Kb + kbase + (size_t)row * 64 + seg * 8);
    }
    // K zero-pad rows 588..591 (cols 0..63)
    if (tid < 256) {
        int r = tid >> 6, cc = tid & 63;
        Ks[(588 + r) * KS_STRIDE + cc] = 0;
    }
    // ---- stage V^T: 64 d-rows x 588 j (147 float2 per row, 16 thr/row)
    {
        int row = tid >> 4, tg = tid & 15;
        const short* src = Vt + vbase + (size_t)row * M_TOT;
        #pragma unroll 2
        for (int jj = tg; jj < 147; jj += 16)
            *(float2*)&Vs[row * VS_STRIDE + jj * 4] = *(const float2*)(src + jj * 4);
    }
    // V zero-pad cols 588..595
    if (tid < 512) {
        int row = tid >> 3, cc = tid & 7;
        Vs[row * VS_STRIDE + 588 + cc] = 0;
    }
    __syncthreads();   // the ONLY barrier

    const bf16x4 ones = {(short)0x3F80, (short)0x3F80, (short)0x3F80, (short)0x3F80};

    // ---- per-wave double-strips: ds covers Q rows q4*784 + ds*32 .. +31
    for (int ds = w; ds < 25; ds += 16) {
        const bool sbv = (ds < 24);           // ds==24: only strip A valid
        const int nA = q4 * 784 + ds * 32 + l15;
        const int nB = sbv ? nA + 16 : nA;    // clamp (compute waste, no store)

        bf16x8 qfA[2], qfB[2];
        #pragma unroll
        for (int ks = 0; ks < 2; ++ks) {
            qfA[ks] = *(const bf16x8*)(Qb + (bh * N_SEQ + nA) * HD + ks * 32 + quad * 8);
            qfB[ks] = *(const bf16x8*)(Qb + (bh * N_SEQ + nB) * HD + ks * 32 + quad * 8);
        }

        f32x4 oaccA[4] = {}, oaccB[4] = {};
        f32x4 rsaccA = {}, rsaccB = {};

        auto LOAD = [&](int j0, bf16x8& K0, bf16x8& K1,
                        bf16x4& V0, bf16x4& V1, bf16x4& V2, bf16x4& V3) {
            const short* kr = &Ks[(j0 + l15) * KS_STRIDE + quad * 8];
            K0 = *(const bf16x8*)kr;
            K1 = *(const bf16x8*)(kr + 32);
            const short* vr = &Vs[l15 * VS_STRIDE + j0 + quad * 4];
            V0 = *(const bf16x4*)vr;
            V1 = *(const bf16x4*)(vr + 16 * VS_STRIDE);
            V2 = *(const bf16x4*)(vr + 32 * VS_STRIDE);
            V3 = *(const bf16x4*)(vr + 48 * VS_STRIDE);
        };

        auto STEP = [&](bf16x8 K0, bf16x8 K1,
                        bf16x4 V0, bf16x4 V1, bf16x4 V2, bf16x4 V3) {
            f32x4 sA = {}, sB = {};
            __builtin_amdgcn_s_setprio(1);
            sA = __builtin_amdgcn_mfma_f32_16x16x32_bf16(K0, qfA[0], sA, 0, 0, 0);
            sB = __builtin_amdgcn_mfma_f32_16x16x32_bf16(K0, qfB[0], sB, 0, 0, 0);
            sA = __builtin_amdgcn_mfma_f32_16x16x32_bf16(K1, qfA[1], sA, 0, 0, 0);
            sB = __builtin_amdgcn_mfma_f32_16x16x32_bf16(K1, qfB[1], sB, 0, 0, 0);
            __builtin_amdgcn_s_setprio(0);

            float pA[4], pB[4];
            #pragma unroll
            for (int r = 0; r < 4; ++r) {
                pA[r] = fexp2(sA[r]);
                pB[r] = fexp2(sB[r]);
            }
            unsigned ua[2] = {pkbf(pA[0], pA[1]), pkbf(pA[2], pA[3])};
            unsigned ub[2] = {pkbf(pB[0], pB[1]), pkbf(pB[2], pB[3])};
            bf16x4 pbA, pbB;
            __builtin_memcpy(&pbA, ua, 8);
            __builtin_memcpy(&pbB, ub, 8);

            __builtin_amdgcn_s_setprio(1);
            // row-sum on the MFMA pipe (A=ones): every lane gets colsum(P)
            rsaccA = mfma16(ones, pbA, rsaccA);
            rsaccB = mfma16(ones, pbB, rsaccB);

            // PV: O^T[d][i] += V^T[d][j] P^T[j][i] (pad j: V=0 -> no effect)
            oaccA[0] = mfma16(V0, pbA, oaccA[0]);
            oaccB[0] = mfma16(V0, pbB, oaccB[0]);
            oaccA[1] = mfma16(V1, pbA, oaccA[1]);
            oaccB[1] = mfma16(V1, pbB, oaccB[1]);
            oaccA[2] = mfma16(V2, pbA, oaccA[2]);
            oaccB[2] = mfma16(V2, pbB, oaccB[2]);
            oaccA[3] = mfma16(V3, pbA, oaccA[3]);
            oaccB[3] = mfma16(V3, pbB, oaccB[3]);
            __builtin_amdgcn_s_setprio(0);
        };

        // ping-pong frag sets; prefetch distance = 1 j-step (16 rows).
        bf16x8 k0a, k1a, k0b, k1b;
        bf16x4 v0a, v1a, v2a, v3a, v0b, v1b, v2b, v3b;

        LOAD(0, k0a, k1a, v0a, v1a, v2a, v3a);
        __builtin_amdgcn_sched_barrier(0);
        #pragma unroll 1
        for (int t = 0; t < 18; ++t) {
            const int j0 = t * 32;
            LOAD(j0 + 16, k0b, k1b, v0b, v1b, v2b, v3b);
            __builtin_amdgcn_sched_barrier(0);
            STEP(k0a, k1a, v0a, v1a, v2a, v3a);
            LOAD(j0 + 32, k0a, k1a, v0a, v1a, v2a, v3a);
            __builtin_amdgcn_sched_barrier(0);
            STEP(k0b, k1b, v0b, v1b, v2b, v3b);
        }
        STEP(k0a, k1a, v0a, v1a, v2a, v3a);   // final step, j0 = 576

        // ---- epilogue: rs is already the full column sum in every lane.
        // Pad rows j=588..591 contributed exp2(0)=1 each -> subtract 4.
        const float invA = 1.f / (rsaccA[0] - 4.f);
        const float invB = 1.f / (rsaccB[0] - 4.f);
        float* orowA = out + ((size_t)b * N_SEQ + nA) * C_DIM + h * HD;
        #pragma unroll
        for (int dt = 0; dt < 4; ++dt) {
            float4 o;
            o.x = oaccA[dt][0] * invA; o.y = oaccA[dt][1] * invA;
            o.z = oaccA[dt][2] * invA; o.w = oaccA[dt][3] * invA;
            *(float4*)&orowA[dt * 16 + quad * 4] = o;
        }
        if (sbv) {
            float* orowB = out + ((size_t)b * N_SEQ + nB) * C_DIM + h * HD;
            #pragma unroll
            for (int dt = 0; dt < 4; ++dt) {
                float4 o;
                o.x = oaccB[dt][0] * invB; o.y = oaccB[dt][1] * invB;
                o.z = oaccB[dt][2] * invB; o.w = oaccB[dt][3] * invB;
                *(float4*)&orowB[dt * 16 + quad * 4] = o;
            }
        }
    }
}

// ---------------------------------------------------------------------------
// Workspace layout (best-measured R5 config):
//   Xb    : ws + 0          (25,690,112)  — written K1, read K2
//   Wqb   : ws + 25,690,112 (   524,288)  — written K1, read K2
//   Wkvb  : ws + 26,214,400 ( 1,048,576)  — written K1, read K4
//   l_pre : ws + 27,262,976 ( 9,633,792)  — written K1, read K2/K3;
//   Kb/Vt :   same region                — written K4 (l_pre dead), read K5
//   Qb    : ws + 36,896,768 (25,690,112)  — written K2, read K5
// stats/Lb live in d_out (first 4.9 MB); consumed by K3/K4, then K5 (attn)
// overwrites every element of out.
// ---------------------------------------------------------------------------
extern "C" void kernel_launch(void* const* d_in, const int* in_sizes, int n_in,
                              void* d_out, int out_size, void* d_ws, size_t ws_size,
                              hipStream_t stream) {
    const float* x     = (const float*)d_in[0];
    const float* Wq    = (const float*)d_in[1];
    const float* bq    = (const float*)d_in[2];
    const float* Wkv   = (const float*)d_in[3];
    const float* bkv   = (const float*)d_in[4];
    const float* w1a   = (const float*)d_in[5];
    const float* b1a   = (const float*)d_in[6];
    const float* w1b   = (const float*)d_in[7];
    const float* b1b   = (const float*)d_in[8];
    const float* w2    = (const float*)d_in[9];
    const float* b2    = (const float*)d_in[10];
    const float* w3    = (const float*)d_in[11];
    const float* b3    = (const float*)d_in[12];
    const float* gamma = (const float*)d_in[13];
    const float* beta  = (const float*)d_in[14];
    float* out = (float*)d_out;

    char* ws = (char*)d_ws;
    short*  Xb    = (short*)ws;
    short*  Wqb   = (short*)(ws + 25690112);
    short*  Wkvb  = (short*)(ws + 26214400);
    float*  l_pre = (float*)(ws + 27262976);       // shares region with Kb/Vt
    short*  Kb    = (short*)(ws + 27262976);       // written after l_pre dead
    short*  Vt    = (short*)(ws + 32079872);
    short*  Qb    = (short*)(ws + 36896768);
    float2* stats = (float2*)d_out;                // 37,632 B in out-buffer
    short*  Lb    = (short*)((char*)d_out + 65536); // 4,849,664 B in out-buffer

    hipFuncSetAttribute((const void*)k_attn,
                        hipFuncAttributeMaxDynamicSharedMemorySize,
                        ATTN_LDS_BYTES);

    k_front<<<8000, 256, 0, stream>>>(
        x, Wq, Wkv, Wqb, Wkvb, Xb,
        w1a, b1a, w1b, b1b, w2, b2, w3, b3, l_pre);
    k_mid<<<864, 256, 0, stream>>>(Xb, Wqb, bq, Qb, l_pre, stats);
    k_lnt<<<dim3(10, 8, BATCH), 256, 0, stream>>>(l_pre, stats, gamma, beta, Lb);
    k_gemm_kv<<<dim3(37, 8), 256, 0, stream>>>(Lb, Wkvb, bkv, Kb, Vt);
    k_attn<<<dim3(4, HEADS, BATCH), 1024, ATTN_LDS_BYTES, stream>>>(Qb, Kb, Vt, out);
}

// Round 13
// 253.822 us; speedup vs baseline: 1.5271x; 1.0166x over previous
//
#include <hip/hip_runtime.h>
#include <hip/hip_bf16.h>

#define BATCH   8
#define C_DIM   512
#define HWD     56
#define NPIX    3136   // 56*56
#define PW      14
#define PP      196    // 14*14
#define M_TOT   588    // 3*196
#define BM_ROWS 4704   // 8*588
#define BM_PAD  4736   // padded to 37*128
#define HEADS   8
#define HD      64
#define N_SEQ   3136
#define SM_SCALE 0.125f
// SM_SCALE * log2(e): folded into Q at the q-GEMM epilogue, so the attention
// inner loop computes p = exp2(s) with NO multiply at all.
#define SM_SCALE_LOG2E 0.1803368801111204f

// attention LDS geometry (measured best: whole-head K+V resident, 1 blk/CU)
#define KS_STRIDE 68            // shorts per K row (34 words: frag reads <=2-way)
#define KS_ROWS   592           // 588 + 4 zero pad rows
#define VS_STRIDE 596           // shorts per V^T row (298 words: <=2-way)
#define ATTN_LDS_SHORTS (KS_ROWS * KS_STRIDE + 64 * VS_STRIDE)   // 78400
#define ATTN_LDS_BYTES  (ATTN_LDS_SHORTS * 2)                    // 156800

typedef __attribute__((ext_vector_type(8))) short bf16x8;
typedef __attribute__((ext_vector_type(4))) short bf16x4;
typedef __attribute__((ext_vector_type(4))) float f32x4;

__device__ __forceinline__ short f2bs(float f) {
    __hip_bfloat16 h = __float2bfloat16(f);
    return *reinterpret_cast<short*>(&h);
}
__device__ __forceinline__ unsigned pkbf(float lo, float hi) {
    __hip_bfloat162 t = __float22bfloat162_rn(make_float2(lo, hi));
    return *reinterpret_cast<unsigned*>(&t);
}
__device__ __forceinline__ float fexp2(float x) {
#if __has_builtin(__builtin_amdgcn_exp2f)
    return __builtin_amdgcn_exp2f(x);
#else
    return exp2f(x);
#endif
}

// 16x16x16 bf16 MFMA (K=16): B-operand layout k=quad*4+jj, n=l15 — matches
// the C/D layout of our S^T tiles directly (no transpose needed for PV).
__device__ __forceinline__ f32x4 mfma16(bf16x4 a, bf16x4 b, f32x4 c) {
#if __has_builtin(__builtin_amdgcn_mfma_f32_16x16x16bf16_1k)
    return __builtin_amdgcn_mfma_f32_16x16x16bf16_1k(a, b, c, 0, 0, 0);
#elif __has_builtin(__builtin_amdgcn_mfma_f32_16x16x16_bf16)
    return __builtin_amdgcn_mfma_f32_16x16x16_bf16(a, b, c, 0, 0, 0);
#else
    asm volatile("v_mfma_f32_16x16x16_bf16 %0, %1, %2, %0\n\ts_nop 7\n\ts_nop 1"
                 : "+v"(c) : "v"(a), "v"(b));
    return c;
#endif
}

// async 16B global->LDS copy (m97 pattern, wave-uniform LDS base).
__device__ __forceinline__ void gl_lds16(const void* g, void* l) {
    __builtin_amdgcn_global_load_lds(
        (const __attribute__((address_space(1))) void*)g,
        (__attribute__((address_space(3))) void*)l, 16, 0, 0);
}

// ===========================================================================
// K1: fused front-end — branches (4096) ∪ xpose (3136) ∪ wconv (768).
//
// R12 rewrite of branches: every output pixel (h,w) of all three branches
// depends ONLY on its own 4x4 input patch (l1's (1,4)+(4,1) convs, l2's 4x4
// conv, and the 4x4 mean-pool all read rows 4h..4h+3 x cols 4w..4w+3).
// So: per-thread 4x float4 patch load -> v1/v2/pool entirely in registers ->
// 784 B pools LDS -> ONE barrier -> v3. Deletes the 13.7 KB xs/y1s staging,
// two barriers, and the div/mod 784-element loop; x still read exactly once.
// ===========================================================================

__device__ __forceinline__ void branches_body(
    int c, int b, int tid, float* pools,
    const float* __restrict__ x,
    const float* __restrict__ w1a, const float* __restrict__ b1a,
    const float* __restrict__ w1b, const float* __restrict__ b1b,
    const float* __restrict__ w2,  const float* __restrict__ b2,
    const float* __restrict__ w3,  const float* __restrict__ b3,
    float* __restrict__ l_pre)
{
    float v1 = 0.f, v2 = 0.f;
    int h = 0, w = 0;
    if (tid < PP) {
        h = tid / PW; w = tid % PW;
        const float* xp = x + ((size_t)(b * C_DIM + c)) * NPIX + (h * 4) * HWD + w * 4;
        float4 p0 = *(const float4*)(xp);
        float4 p1 = *(const float4*)(xp + HWD);
        float4 p2 = *(const float4*)(xp + 2 * HWD);
        float4 p3 = *(const float4*)(xp + 3 * HWD);

        // branch 1: (1,4)s(1,4) conv + relu, then (4,1)s(4,1) conv + relu
        const float wa0 = w1a[c*4+0], wa1 = w1a[c*4+1],
                    wa2 = w1a[c*4+2], wa3 = w1a[c*4+3];
        const float ba = b1a[c];
        float y0 = fmaxf(ba + p0.x*wa0 + p0.y*wa1 + p0.z*wa2 + p0.w*wa3, 0.f);
        float y1 = fmaxf(ba + p1.x*wa0 + p1.y*wa1 + p1.z*wa2 + p1.w*wa3, 0.f);
        float y2 = fmaxf(ba + p2.x*wa0 + p2.y*wa1 + p2.z*wa2 + p2.w*wa3, 0.f);
        float y3 = fmaxf(ba + p3.x*wa0 + p3.y*wa1 + p3.z*wa2 + p3.w*wa3, 0.f);
        v1 = fmaxf(b1b[c] + y0*w1b[c*4+0] + y1*w1b[c*4+1]
                          + y2*w1b[c*4+2] + y3*w1b[c*4+3], 0.f);

        // branch 2: 4x4 stride-4 conv + relu
        const float* W2 = w2 + c * 16;
        float a2 = b2[c];
        a2 += p0.x*W2[0]  + p0.y*W2[1]  + p0.z*W2[2]  + p0.w*W2[3];
        a2 += p1.x*W2[4]  + p1.y*W2[5]  + p1.z*W2[6]  + p1.w*W2[7];
        a2 += p2.x*W2[8]  + p2.y*W2[9]  + p2.z*W2[10] + p2.w*W2[11];
        a2 += p3.x*W2[12] + p3.y*W2[13] + p3.z*W2[14] + p3.w*W2[15];
        v2 = fmaxf(a2, 0.f);

        // branch 3 stage 1: 4x4 mean pool
        float s = (p0.x + p0.y + p0.z + p0.w)
                + (p1.x + p1.y + p1.z + p1.w)
                + (p2.x + p2.y + p2.z + p2.w)
                + (p3.x + p3.y + p3.z + p3.w);
        pools[tid] = s * (1.f / 16.f);
    }
    __syncthreads();

    if (tid < PP) {
        // branch 3 stage 2: 3x3 conv pad 1 over pools + relu
        float v3 = b3[c];
        #pragma unroll
        for (int dh = -1; dh <= 1; ++dh)
            #pragma unroll
            for (int dw = -1; dw <= 1; ++dw) {
                int hh = h + dh, ww = w + dw;
                if (hh >= 0 && hh < PW && ww >= 0 && ww < PW)
                    v3 += pools[hh*PW + ww] * w3[c*9 + (dh+1)*3 + (dw+1)];
            }
        v3 = fmaxf(v3, 0.f);

        float* lp = l_pre + ((size_t)(b * C_DIM + c)) * M_TOT;
        lp[tid]        = v1;
        lp[PP + tid]   = v2;
        lp[2*PP + tid] = v3;
    }
}

__device__ __forceinline__ void xpose_body(
    int bx, int by, int bz, int tid, float* sbuf,
    const float* __restrict__ x, short* __restrict__ Xb)
{
    float (*sx)[68] = (float(*)[68])sbuf;
    const int n0 = bx * 64, c0 = by * 64, b = bz;
    #pragma unroll
    for (int it = 0; it < 4; ++it) {
        int idx = tid + it * 256;
        int cr = idx >> 4, n4 = (idx & 15) * 4;
        float4 v = *(const float4*)(x + ((size_t)(b * C_DIM + c0 + cr)) * NPIX + n0 + n4);
        *(float4*)&sx[cr][n4] = v;
    }
    __syncthreads();
    #pragma unroll
    for (int p = 0; p < 2; ++p) {
        int idx = tid + p * 256;
        int nr = idx >> 3, cg = (idx & 7) * 8;
        short ov[8];
        #pragma unroll
        for (int e = 0; e < 8; ++e) ov[e] = f2bs(sx[cg + e][nr]);
        *(float4*)&Xb[((size_t)(b * NPIX + n0 + nr)) * C_DIM + c0 + cg] = *(float4*)ov;
    }
}

__device__ __forceinline__ void wconv_body(
    int blk, int tid,
    const float* __restrict__ Wq, const float* __restrict__ Wkv,
    short* __restrict__ Wqb, short* __restrict__ Wkvb)
{
    int i = (blk * 256 + tid) * 4;
    if (i < 262144) {
        float4 v = *(const float4*)(Wq + i);
        short o[4] = {f2bs(v.x), f2bs(v.y), f2bs(v.z), f2bs(v.w)};
        *(short4*)(Wqb + i) = *(short4*)o;
    } else {
        int j = i - 262144;
        float4 v = *(const float4*)(Wkv + j);
        short o[4] = {f2bs(v.x), f2bs(v.y), f2bs(v.z), f2bs(v.w)};
        *(short4*)(Wkvb + j) = *(short4*)o;
    }
}

__global__ __launch_bounds__(256) void k_front(
    const float* __restrict__ x,
    const float* __restrict__ Wq, const float* __restrict__ Wkv,
    short* __restrict__ Wqb, short* __restrict__ Wkvb,
    short* __restrict__ Xb,
    const float* __restrict__ w1a, const float* __restrict__ b1a,
    const float* __restrict__ w1b, const float* __restrict__ b1b,
    const float* __restrict__ w2,  const float* __restrict__ b2,
    const float* __restrict__ w3,  const float* __restrict__ b3,
    float* __restrict__ l_pre)
{
    __shared__ float sbuf[4368];   // xpose 4352; branches uses first 196
    const int bid = blockIdx.x, tid = threadIdx.x;
    if (bid < 4096) {
        branches_body(bid & 511, bid >> 9, tid, sbuf,
                      x, w1a, b1a, w1b, b1b, w2, b2, w3, b3, l_pre);
    } else if (bid < 7232) {
        int i2 = bid - 4096;               // 3136 = 49*8*8
        xpose_body(i2 % 49, (i2 / 49) & 7, i2 / 392, tid, sbuf, x, Xb);
    } else {
        wconv_body(bid - 7232, tid, Wq, Wkv, Wqb, Wkvb);
    }
}

// ===========================================================================
// K2: fused mid — gemm_q (784 blocks) ∪ stats (80 blocks).
// ===========================================================================

__device__ __forceinline__ void gemm_q_body(
    int bx, int by, int tid, short* As, short* Bs,
    const short* __restrict__ A, const short* __restrict__ Bw,
    const float* __restrict__ bias, short* __restrict__ Qb)
{
    const int lane = tid & 63, w = tid >> 6;
    const int l15 = lane & 15, quad = lane >> 4;
    const int wr = w & 1, wc = w >> 1;
    const int row0 = bx * 128, col0 = by * 128;
    const int lr8 = lane >> 3, lc8 = (lane & 7) * 8;

    f32x4 acc[4][4] = {};

    for (int c0 = 0; c0 < 512; c0 += 64) {
        __syncthreads();
        #pragma unroll
        for (int it = 0; it < 4; ++it) {
            int r = w * 32 + it * 8;
            gl_lds16(A  + (size_t)(row0 + r + lr8) * 512 + c0 + lc8, &As[r * 64]);
            gl_lds16(Bw + (size_t)(col0 + r + lr8) * 512 + c0 + lc8, &Bs[r * 64]);
        }
        __syncthreads();
        #pragma unroll
        for (int ks = 0; ks < 2; ++ks) {
            bf16x8 af[4], bf[4];
            #pragma unroll
            for (int t = 0; t < 4; ++t) {
                af[t] = *(const bf16x8*)&As[(wr*64 + t*16 + l15)*64 + ks*32 + quad*8];
                bf[t] = *(const bf16x8*)&Bs[(wc*64 + t*16 + l15)*64 + ks*32 + quad*8];
            }
            #pragma unroll
            for (int nt = 0; nt < 4; ++nt)
                #pragma unroll
                for (int mt = 0; mt < 4; ++mt)
                    acc[nt][mt] = __builtin_amdgcn_mfma_f32_16x16x32_bf16(
                        af[nt], bf[mt], acc[nt][mt], 0, 0, 0);
        }
    }

    #pragma unroll
    for (int nt = 0; nt < 4; ++nt) {
        int row_t = row0 + wr * 64 + nt * 16 + quad * 4;
        #pragma unroll
        for (int mt = 0; mt < 4; ++mt) {
            int col = col0 + wc * 64 + mt * 16 + l15;
            float bv = bias[col];
            int h = col >> 6, d = col & 63;
            #pragma unroll
            for (int r = 0; r < 4; ++r) {
                int row_g = row_t + r;
                int b = row_g / N_SEQ;
                int n = row_g - b * N_SEQ;
                Qb[(((size_t)(b * HEADS + h)) * N_SEQ + n) * HD + d] =
                    f2bs((acc[nt][mt][r] + bv) * SM_SCALE_LOG2E);
            }
        }
    }
}

__device__ __forceinline__ void stats_body(
    int sx_, int sb_, int tid, float* red,
    const float* __restrict__ l_pre, float2* __restrict__ stats)
{
    float* ssum = red;
    float* ssq  = red + 256;
    const int ml = tid & 63, cg = tid >> 6;
    const int b = sb_;
    const int m = sx_ * 64 + ml;
    float s = 0.f, q = 0.f;
    if (m < M_TOT) {
        const float* base = l_pre + ((size_t)b * C_DIM + cg * 128) * M_TOT + m;
        for (int c = 0; c < 128; ++c) {
            float v = base[(size_t)c * M_TOT];
            s += v; q += v * v;
        }
    }
    ssum[cg*64 + ml] = s; ssq[cg*64 + ml] = q;
    __syncthreads();
    if (tid < 64 && sx_ * 64 + tid < M_TOT) {
        float ts = ssum[tid] + ssum[64+tid] + ssum[128+tid] + ssum[192+tid];
        float tq = ssq[tid] + ssq[64+tid] + ssq[128+tid] + ssq[192+tid];
        float mu = ts * (1.f / 512.f);
        float var = tq * (1.f / 512.f) - mu * mu;
        stats[(size_t)b * M_TOT + sx_ * 64 + tid] =
            make_float2(mu, rsqrtf(var + 1e-5f));
    }
}

__global__ __launch_bounds__(256) void k_mid(
    const short* __restrict__ Xb, const short* __restrict__ Wqb,
    const float* __restrict__ bq, short* __restrict__ Qb,
    const float* __restrict__ l_pre, float2* __restrict__ stats)
{
    __shared__ short sb2[16384];   // gemm: As|Bs (32 KB); stats: 2 KB reduce
    const int bid = blockIdx.x, tid = threadIdx.x;
    if (bid < 784) {
        gemm_q_body(bid % 196, bid / 196, tid, sb2, sb2 + 8192,
                    Xb, Wqb, bq, Qb);
    } else {
        int sid = bid - 784;       // 80 = 10*8
        stats_body(sid % 10, sid / 10, tid, (float*)sb2, l_pre, stats);
    }
}

// ---------------------------------------------------------------------------
// Kernel L: LN(l_pre) transposed -> Lb [BM_PAD, C] bf16.
// ---------------------------------------------------------------------------
__global__ __launch_bounds__(256) void k_lnt(
    const float* __restrict__ l_pre, const float2* __restrict__ stats,
    const float* __restrict__ gamma, const float* __restrict__ beta,
    short* __restrict__ Lb)
{
    __shared__ float sx[64][68];
    const int tid = threadIdx.x;
    const int m0 = blockIdx.x * 64, c0 = blockIdx.y * 64, b = blockIdx.z;
    #pragma unroll
    for (int it = 0; it < 4; ++it) {
        int idx = tid + it * 256;
        int cr = idx >> 4, m4 = (idx & 15) * 4;
        float4 v = {0.f, 0.f, 0.f, 0.f};
        if (m0 + m4 < M_TOT)
            v = *(const float4*)(l_pre + ((size_t)(b * C_DIM + c0 + cr)) * M_TOT + m0 + m4);
        *(float4*)&sx[cr][m4] = v;
    }
    __syncthreads();
    #pragma unroll
    for (int p = 0; p < 2; ++p) {
        int idx = tid + p * 256;
        int mr = idx >> 3, cg = (idx & 7) * 8;
        int m = m0 + mr;
        float mu = 0.f, rstd = 0.f;
        if (m < M_TOT) {
            float2 st = stats[(size_t)b * M_TOT + m];
            mu = st.x; rstd = st.y;
        }
        short ov[8];
        #pragma unroll
        for (int e = 0; e < 8; ++e) {
            int c = c0 + cg + e;
            ov[e] = f2bs((sx[cg + e][mr] - mu) * rstd * gamma[c] + beta[c]);
        }
        if (m < M_TOT)
            *(float4*)&Lb[((size_t)(b * M_TOT + m)) * C_DIM + c0 + cg] = *(float4*)ov;
    }
}

// ---------------------------------------------------------------------------
// K4: kv GEMM (staged m97 pattern).
// ---------------------------------------------------------------------------
__global__ __launch_bounds__(256) void k_gemm_kv(
    const short* __restrict__ A, const short* __restrict__ Bw,
    const float* __restrict__ bias,
    short* __restrict__ Kb, short* __restrict__ Vt)
{
    __shared__ short As[128 * 64];
    __shared__ short Bs[128 * 64];
    const int tid = threadIdx.x;
    const int lane = tid & 63, w = tid >> 6;
    const int l15 = lane & 15, quad = lane >> 4;
    const int wr = w & 1, wc = w >> 1;
    const int row0 = blockIdx.x * 128, col0 = blockIdx.y * 128;
    const int lr8 = lane >> 3, lc8 = (lane & 7) * 8;

    f32x4 acc[4][4] = {};

    for (int c0 = 0; c0 < 512; c0 += 64) {
        __syncthreads();
        #pragma unroll
        for (int it = 0; it < 4; ++it) {
            int r = w * 32 + it * 8;
            gl_lds16(A  + (size_t)(row0 + r + lr8) * 512 + c0 + lc8, &As[r * 64]);
            gl_lds16(Bw + (size_t)(col0 + r + lr8) * 512 + c0 + lc8, &Bs[r * 64]);
        }
        __syncthreads();
        #pragma unroll
        for (int ks = 0; ks < 2; ++ks) {
            bf16x8 af[4], bf[4];
            #pragma unroll
            for (int t = 0; t < 4; ++t) {
                af[t] = *(const bf16x8*)&As[(wr*64 + t*16 + l15)*64 + ks*32 + quad*8];
                bf[t] = *(const bf16x8*)&Bs[(wc*64 + t*16 + l15)*64 + ks*32 + quad*8];
            }
            #pragma unroll
            for (int nt = 0; nt < 4; ++nt)
                #pragma unroll
                for (int mt = 0; mt < 4; ++mt)
                    acc[nt][mt] = __builtin_amdgcn_mfma_f32_16x16x32_bf16(
                        af[nt], bf[mt], acc[nt][mt], 0, 0, 0);
        }
    }

    #pragma unroll
    for (int nt = 0; nt < 4; ++nt) {
        int row_t = row0 + wr * 64 + nt * 16 + quad * 4;
        #pragma unroll
        for (int mt = 0; mt < 4; ++mt) {
            int col = col0 + wc * 64 + mt * 16 + l15;
            float bv = bias[col];
            #pragma unroll
            for (int r = 0; r < 4; ++r) {
                int row_g = row_t + r;
                float v = acc[nt][mt][r] + bv;
                if (row_g < BM_ROWS) {
                    int b = row_g / M_TOT;
                    int m = row_g - b * M_TOT;
                    if (col < 512) {
                        int h = col >> 6, d = col & 63;
                        Kb[(((size_t)(b * HEADS + h)) * M_TOT + m) * HD + d] = f2bs(v);
                    } else {
                        int jj = col - 512, h = jj >> 6, d = jj & 63;
                        Vt[(((size_t)(b * HEADS + h)) * HD + d) * M_TOT + m] = f2bs(v);
                    }
                }
            }
        }
    }
}

// ---------------------------------------------------------------------------
// Kernel E: persistent-KV MFMA attention (best-measured config, ~77 µs).
// Grid (4, h, b) = 256 blocks, 16 waves, 156.8 KB LDS, 1 block/CU.
// Work-distribution-optimal: 49 strips / 16 waves -> critical wave = 4
// strips + 2 load phases, which this 2-round double-strip schedule achieves.
// ---------------------------------------------------------------------------
__global__ __launch_bounds__(1024) void k_attn(
    const short* __restrict__ Qb, const short* __restrict__ Kb,
    const short* __restrict__ Vt, float* __restrict__ out)
{
    extern __shared__ short smem[];
    short* Ks = smem;                       // [592][68]
    short* Vs = smem + KS_ROWS * KS_STRIDE; // [64][596]

    const int tid = threadIdx.x;
    const int lane = tid & 63, w = tid >> 6;
    const int l15 = lane & 15, quad = lane >> 4;
    const int q4 = blockIdx.x, h = blockIdx.y, b = blockIdx.z;
    const size_t bh = (size_t)(b * HEADS + h);
    const size_t kbase = bh * M_TOT * HD;          // Kb [B,h,M,d]
    const size_t vbase = bh * (size_t)HD * M_TOT;  // Vt [B,h,d,M]

    // ---- stage K: 588 rows x 64 d (4704 float4 over 1024 threads)
    for (int i = tid; i < 4704; i += 1024) {
        int row = i >> 3, seg = i & 7;
        *(float4*)&Ks[row * KS_STRIDE + seg * 8] =
            *(const float4*)(Kb + kbase + (size_t)row * 64 + seg * 8);
    }
    // K zero-pad rows 588..591 (cols 0..63)
    if (tid < 256) {
        int r = tid >> 6, cc = tid & 63;
        Ks[(588 + r) * KS_STRIDE + cc] = 0;
    }
    // ---- stage V^T: 64 d-rows x 588 j (147 float2 per row, 16 thr/row)
    {
        int row = tid >> 4, tg = tid & 15;
        const short* src = Vt + vbase + (size_t)row * M_TOT;
        #pragma unroll 2
        for (int jj = tg; jj < 147; jj += 16)
            *(float2*)&Vs[row * VS_STRIDE + jj * 4] = *(const float2*)(src + jj * 4);
    }
    // V zero-pad cols 588..595
    if (tid < 512) {
        int row = tid >> 3, cc = tid & 7;
        Vs[row * VS_STRIDE + 588 + cc] = 0;
    }
    __syncthreads();   // the ONLY barrier

    const bf16x4 ones = {(short)0x3F80, (short)0x3F80, (short)0x3F80, (short)0x3F80};

    // ---- per-wave double-strips: ds covers Q rows q4*784 + ds*32 .. +31
    for (int ds = w; ds < 25; ds += 16) {
        const bool sbv = (ds < 24);           // ds==24: only strip A valid
        const int nA = q4 * 784 + ds * 32 + l15;
        const int nB = sbv ? nA + 16 : nA;    // clamp (compute waste, no store)

        bf16x8 qfA[2], qfB[2];
        #pragma unroll
        for (int ks = 0; ks < 2; ++ks) {
            qfA[ks] = *(const bf16x8*)(Qb + (bh * N_SEQ + nA) * HD + ks * 32 + quad * 8);
            qfB[ks] = *(const bf16x8*)(Qb + (bh * N_SEQ + nB) * HD + ks * 32 + quad * 8);
        }

        f32x4 oaccA[4] = {}, oaccB[4] = {};
        f32x4 rsaccA = {}, rsaccB = {};

        auto LOAD = [&](int j0, bf16x8& K0, bf16x8& K1,
                        bf16x4& V0, bf16x4& V1, bf16x4& V2, bf16x4& V3) {
            const short* kr = &Ks[(j0 + l15) * KS_STRIDE + quad * 8];
            K0 = *(const bf16x8*)kr;
            K1 = *(const bf16x8*)(kr + 32);
            const short* vr = &Vs[l15 * VS_STRIDE + j0 + quad * 4];
            V0 = *(const bf16x4*)vr;
            V1 = *(const bf16x4*)(vr + 16 * VS_STRIDE);
            V2 = *(const bf16x4*)(vr + 32 * VS_STRIDE);
            V3 = *(const bf16x4*)(vr + 48 * VS_STRIDE);
        };

        auto STEP = [&](bf16x8 K0, bf16x8 K1,
                        bf16x4 V0, bf16x4 V1, bf16x4 V2, bf16x4 V3) {
            f32x4 sA = {}, sB = {};
            __builtin_amdgcn_s_setprio(1);
            sA = __builtin_amdgcn_mfma_f32_16x16x32_bf16(K0, qfA[0], sA, 0, 0, 0);
            sB = __builtin_amdgcn_mfma_f32_16x16x32_bf16(K0, qfB[0], sB, 0, 0, 0);
            sA = __builtin_amdgcn_mfma_f32_16x16x32_bf16(K1, qfA[1], sA, 0, 0, 0);
            sB = __builtin_amdgcn_mfma_f32_16x16x32_bf16(K1, qfB[1], sB, 0, 0, 0);
            __builtin_amdgcn_s_setprio(0);

            float pA[4], pB[4];
            #pragma unroll
            for (int r = 0; r < 4; ++r) {
                pA[r] = fexp2(sA[r]);
                pB[r] = fexp2(sB[r]);
            }
            unsigned ua[2] = {pkbf(pA[0], pA[1]), pkbf(pA[2], pA[3])};
            unsigned ub[2] = {pkbf(pB[0], pB[1]), pkbf(pB[2], pB[3])};
            bf16x4 pbA, pbB;
            __builtin_memcpy(&pbA, ua, 8);
            __builtin_memcpy(&pbB, ub, 8);

            __builtin_amdgcn_s_setprio(1);
            // row-sum on the MFMA pipe (A=ones): every lane gets colsum(P)
            rsaccA = mfma16(ones, pbA, rsaccA);
            rsaccB = mfma16(ones, pbB, rsaccB);

            // PV: O^T[d][i] += V^T[d][j] P^T[j][i] (pad j: V=0 -> no effect)
            oaccA[0] = mfma16(V0, pbA, oaccA[0]);
            oaccB[0] = mfma16(V0, pbB, oaccB[0]);
            oaccA[1] = mfma16(V1, pbA, oaccA[1]);
            oaccB[1] = mfma16(V1, pbB, oaccB[1]);
            oaccA[2] = mfma16(V2, pbA, oaccA[2]);
            oaccB[2] = mfma16(V2, pbB, oaccB[2]);
            oaccA[3] = mfma16(V3, pbA, oaccA[3]);
            oaccB[3] = mfma16(V3, pbB, oaccB[3]);
            __builtin_amdgcn_s_setprio(0);
        };

        // ping-pong frag sets; prefetch distance = 1 j-step (16 rows).
        bf16x8 k0a, k1a, k0b, k1b;
        bf16x4 v0a, v1a, v2a, v3a, v0b, v1b, v2b, v3b;

        LOAD(0, k0a, k1a, v0a, v1a, v2a, v3a);
        __builtin_amdgcn_sched_barrier(0);
        #pragma unroll 1
        for (int t = 0; t < 18; ++t) {
            const int j0 = t * 32;
            LOAD(j0 + 16, k0b, k1b, v0b, v1b, v2b, v3b);
            __builtin_amdgcn_sched_barrier(0);
            STEP(k0a, k1a, v0a, v1a, v2a, v3a);
            LOAD(j0 + 32, k0a, k1a, v0a, v1a, v2a, v3a);
            __builtin_amdgcn_sched_barrier(0);
            STEP(k0b, k1b, v0b, v1b, v2b, v3b);
        }
        STEP(k0a, k1a, v0a, v1a, v2a, v3a);   // final step, j0 = 576

        // ---- epilogue: rs is already the full column sum in every lane.
        // Pad rows j=588..591 contributed exp2(0)=1 each -> subtract 4.
        const float invA = 1.f / (rsaccA[0] - 4.f);
        const float invB = 1.f / (rsaccB[0] - 4.f);
        float* orowA = out + ((size_t)b * N_SEQ + nA) * C_DIM + h * HD;
        #pragma unroll
        for (int dt = 0; dt < 4; ++dt) {
            float4 o;
            o.x = oaccA[dt][0] * invA; o.y = oaccA[dt][1] * invA;
            o.z = oaccA[dt][2] * invA; o.w = oaccA[dt][3] * invA;
            *(float4*)&orowA[dt * 16 + quad * 4] = o;
        }
        if (sbv) {
            float* orowB = out + ((size_t)b * N_SEQ + nB) * C_DIM + h * HD;
            #pragma unroll
            for (int dt = 0; dt < 4; ++dt) {
                float4 o;
                o.x = oaccB[dt][0] * invB; o.y = oaccB[dt][1] * invB;
                o.z = oaccB[dt][2] * invB; o.w = oaccB[dt][3] * invB;
                *(float4*)&orowB[dt * 16 + quad * 4] = o;
            }
        }
    }
}

// ---------------------------------------------------------------------------
// Workspace layout (best-measured config):
//   Xb    : ws + 0          (25,690,112)  — written K1, read K2
//   Wqb   : ws + 25,690,112 (   524,288)  — written K1, read K2
//   Wkvb  : ws + 26,214,400 ( 1,048,576)  — written K1, read K4
//   l_pre : ws + 27,262,976 ( 9,633,792)  — written K1, read K2/K3;
//   Kb/Vt :   same region                — written K4 (l_pre dead), read K5
//   Qb    : ws + 36,896,768 (25,690,112)  — written K2, read K5
// stats/Lb live in d_out (first 4.9 MB); consumed by K3/K4, then K5 (attn)
// overwrites every element of out.
// ---------------------------------------------------------------------------
extern "C" void kernel_launch(void* const* d_in, const int* in_sizes, int n_in,
                              void* d_out, int out_size, void* d_ws, size_t ws_size,
                              hipStream_t stream) {
    const float* x     = (const float*)d_in[0];
    const float* Wq    = (const float*)d_in[1];
    const float* bq    = (const float*)d_in[2];
    const float* Wkv   = (const float*)d_in[3];
    const float* bkv   = (const float*)d_in[4];
    const float* w1a   = (const float*)d_in[5];
    const float* b1a   = (const float*)d_in[6];
    const float* w1b   = (const float*)d_in[7];
    const float* b1b   = (const float*)d_in[8];
    const float* w2    = (const float*)d_in[9];
    const float* b2    = (const float*)d_in[10];
    const float* w3    = (const float*)d_in[11];
    const float* b3    = (const float*)d_in[12];
    const float* gamma = (const float*)d_in[13];
    const float* beta  = (const float*)d_in[14];
    float* out = (float*)d_out;

    char* ws = (char*)d_ws;
    short*  Xb    = (short*)ws;
    short*  Wqb   = (short*)(ws + 25690112);
    short*  Wkvb  = (short*)(ws + 26214400);
    float*  l_pre = (float*)(ws + 27262976);       // shares region with Kb/Vt
    short*  Kb    = (short*)(ws + 27262976);       // written after l_pre dead
    short*  Vt    = (short*)(ws + 32079872);
    short*  Qb    = (short*)(ws + 36896768);
    float2* stats = (float2*)d_out;                // 37,632 B in out-buffer
    short*  Lb    = (short*)((char*)d_out + 65536); // 4,849,664 B in out-buffer

    hipFuncSetAttribute((const void*)k_attn,
                        hipFuncAttributeMaxDynamicSharedMemorySize,
                        ATTN_LDS_BYTES);

    k_front<<<8000, 256, 0, stream>>>(
        x, Wq, Wkv, Wqb, Wkvb, Xb,
        w1a, b1a, w1b, b1b, w2, b2, w3, b3, l_pre);
    k_mid<<<864, 256, 0, stream>>>(Xb, Wqb, bq, Qb, l_pre, stats);
    k_lnt<<<dim3(10, 8, BATCH), 256, 0, stream>>>(l_pre, stats, gamma, beta, Lb);
    k_gemm_kv<<<dim3(37, 8), 256, 0, stream>>>(Lb, Wkvb, bkv, Kb, Vt);
    k_attn<<<dim3(4, HEADS, BATCH), 1024, ATTN_LDS_BYTES, stream>>>(Qb, Kb, Vt, out);
}